// Round 1
// baseline (638.734 us; speedup 1.0000x reference)
//
#include <hip/hip_runtime.h>
#include <cstdint>
#include <cstddef>

#define S_LEN 2048
#define DIM_   2048
#define NH   16
#define NKV  8
#define HD   128

typedef __attribute__((ext_vector_type(8))) __bf16 bf16x8;
typedef __attribute__((ext_vector_type(4))) float  f32x4;

static __device__ __forceinline__ float bf2f(unsigned short u) {
  union { unsigned int i; float f; } v; v.i = ((unsigned int)u) << 16; return v.f;
}
static __device__ __forceinline__ unsigned short f2bf(float f) {
  union { float f; unsigned int i; } v; v.f = f;
  unsigned int u = v.i;
  unsigned int r = (u + 0x7FFFu + ((u >> 16) & 1u)) >> 16;
  return (unsigned short)r;
}

// ---------------- fp32 -> bf16 convert (vectorized) ----------------
__global__ void k_f32_to_bf16(const float* __restrict__ in, unsigned short* __restrict__ out, int n4) {
  int i = blockIdx.x * 256 + threadIdx.x;
  if (i >= n4) return;
  float4 v = ((const float4*)in)[i];
  ushort4 o; o.x = f2bf(v.x); o.y = f2bf(v.y); o.z = f2bf(v.z); o.w = f2bf(v.w);
  ((ushort4*)out)[i] = o;
}

// ------------- transpose + convert: w(K,N) f32 -> wt(N,K) bf16 -------------
__global__ void k_transpose_bf16(const float* __restrict__ w, unsigned short* __restrict__ wt,
                                 int K, int N) {
  __shared__ float tile[32][33];
  int lx = threadIdx.x & 31, ly = threadIdx.x >> 5; // 32 x 8
  int r0 = blockIdx.y * 32, c0 = blockIdx.x * 32;
  #pragma unroll
  for (int r = 0; r < 32; r += 8)
    tile[ly + r][lx] = w[(size_t)(r0 + ly + r) * N + c0 + lx];
  __syncthreads();
  #pragma unroll
  for (int r = 0; r < 32; r += 8)
    wt[(size_t)(c0 + ly + r) * K + r0 + lx] = f2bf(tile[lx][ly + r]);
}

// ------------- GEMM: C(MxN) = A(MxK) * BT(NxK)^T, bf16 in, fp32 acc -------------
// MODE 0: store bf16 natural C[m][n]
// MODE 1: store f32  natural C[m][n]
// MODE 2: store bf16 V-transposed: vT[(b*NKV+kvh)*HD + d][s]  (n = kvh*HD+d, m = b*S+s)
template<int MODE>
__global__ __launch_bounds__(256) void k_gemm_bt(
    const unsigned short* __restrict__ A, const unsigned short* __restrict__ BT,
    void* __restrict__ C, int N, int K) {
  __shared__ __align__(16) unsigned short Asm[128 * 32];
  __shared__ __align__(16) unsigned short Bsm[128 * 32];
  const int t = threadIdx.x;
  const int lane = t & 63, w = t >> 6;
  const int wm = (w >> 1) * 64, wn = (w & 1) * 64;
  const int col = lane & 15, quad = lane >> 4;
  const int m0 = blockIdx.y * 128, n0 = blockIdx.x * 128;

  f32x4 acc[4][4];
  #pragma unroll
  for (int i = 0; i < 4; i++)
    #pragma unroll
    for (int j = 0; j < 4; j++) acc[i][j] = (f32x4){0.f, 0.f, 0.f, 0.f};

  for (int kk = 0; kk < K; kk += 32) {
    #pragma unroll
    for (int r = 0; r < 2; ++r) {
      int c = t + r * 256;
      int row = c >> 2, kc = c & 3;
      *(uint4*)(&Asm[row * 32 + kc * 8]) = *(const uint4*)(A + (size_t)(m0 + row) * K + kk + kc * 8);
      *(uint4*)(&Bsm[row * 32 + kc * 8]) = *(const uint4*)(BT + (size_t)(n0 + row) * K + kk + kc * 8);
    }
    __syncthreads();
    bf16x8 af[4], bf[4];
    #pragma unroll
    for (int mi = 0; mi < 4; mi++) af[mi] = *(const bf16x8*)(&Asm[(wm + mi * 16 + col) * 32 + quad * 8]);
    #pragma unroll
    for (int ni = 0; ni < 4; ni++) bf[ni] = *(const bf16x8*)(&Bsm[(wn + ni * 16 + col) * 32 + quad * 8]);
    #pragma unroll
    for (int mi = 0; mi < 4; mi++)
      #pragma unroll
      for (int ni = 0; ni < 4; ni++)
        acc[mi][ni] = __builtin_amdgcn_mfma_f32_16x16x32_bf16(af[mi], bf[ni], acc[mi][ni], 0, 0, 0);
    __syncthreads();
  }

  #pragma unroll
  for (int mi = 0; mi < 4; mi++) {
    int row_base = m0 + wm + mi * 16 + quad * 4;
    #pragma unroll
    for (int ni = 0; ni < 4; ni++) {
      int col_g = n0 + wn + ni * 16 + col;
      if (MODE == 0) {
        unsigned short* O = (unsigned short*)C;
        #pragma unroll
        for (int r = 0; r < 4; r++) O[(size_t)(row_base + r) * N + col_g] = f2bf(acc[mi][ni][r]);
      } else if (MODE == 1) {
        float* O = (float*)C;
        #pragma unroll
        for (int r = 0; r < 4; r++) O[(size_t)(row_base + r) * N + col_g] = acc[mi][ni][r];
      } else {
        unsigned short* O = (unsigned short*)C;
        int b = row_base >> 11, s = row_base & (S_LEN - 1);
        int kvh = col_g >> 7, d = col_g & (HD - 1);
        ushort4 o4;
        o4.x = f2bf(acc[mi][ni][0]); o4.y = f2bf(acc[mi][ni][1]);
        o4.z = f2bf(acc[mi][ni][2]); o4.w = f2bf(acc[mi][ni][3]);
        *(ushort4*)(&O[((size_t)((b * NKV + kvh) * HD + d)) * S_LEN + s]) = o4;
      }
    }
  }
}

// ---------------- RoPE (in-place on bf16, pair = adjacent cols) ----------------
__global__ void k_rope(unsigned short* __restrict__ tq, const float* __restrict__ fc,
                       const float* __restrict__ fs, int ncols) {
  int p = blockIdx.x * 256 + threadIdx.x;  // pair index within a row
  int row = blockIdx.y;                    // 0..4095 (b*S+s)
  int half = ncols >> 1;
  if (p >= half) return;
  int s = row & (S_LEN - 1);
  int i = p & 63;  // (col % 128) / 2
  float c = fc[s * 64 + i], sn = fs[s * 64 + i];
  unsigned short* ptr = tq + (size_t)row * ncols + 2 * p;
  float p1 = bf2f(ptr[0]), p2 = bf2f(ptr[1]);
  ushort2 o; o.x = f2bf(p1 * c - p2 * sn); o.y = f2bf(p1 * sn + p2 * c);
  *(ushort2*)ptr = o;
}

// ---------------- Flash attention, causal, GQA (kvh = h>>1) ----------------
// q: (b,s,h,d) bf16 ld=2048 ; k: (b,s,kvh,d) bf16 ld=1024 ; vT: (b,kvh,d,s) bf16 ld=2048
// ao: (b,s,h,d) bf16 ld=2048
__global__ __launch_bounds__(256) void k_attn(
    const unsigned short* __restrict__ q, const unsigned short* __restrict__ k,
    const unsigned short* __restrict__ vT, unsigned short* __restrict__ ao) {
  __shared__ __align__(16) unsigned short Ksm[64 * 128];
  __shared__ __align__(16) unsigned short Vsm[128 * 64];
  __shared__ __align__(16) unsigned short Psm[4][16 * 64];
  const int t = threadIdx.x;
  const int lane = t & 63, w = t >> 6;
  const int col = lane & 15, quad = lane >> 4;
  const int bh = blockIdx.y;
  const int b = bh >> 4, h = bh & 15, kvh = h >> 1;
  const int q0 = blockIdx.x * 64;
  const int qrow = q0 + w * 16;  // this wave's 16 query rows start here

  // Q fragments (A-operand layout), kept in registers for the whole block
  bf16x8 qf[4];
  const size_t qbase = ((size_t)(b * S_LEN) + qrow + col) * DIM_ + h * HD;
  #pragma unroll
  for (int kc = 0; kc < 4; kc++) qf[kc] = *(const bf16x8*)(q + qbase + kc * 32 + quad * 8);

  f32x4 o[8];
  #pragma unroll
  for (int i = 0; i < 8; i++) o[i] = (f32x4){0.f, 0.f, 0.f, 0.f};
  float m_i[4] = {-1e30f, -1e30f, -1e30f, -1e30f};
  float l_i[4] = {0.f, 0.f, 0.f, 0.f};
  const float scale = 0.08838834764831845f;  // 1/sqrt(128)

  const int nkt = q0 / 64 + 1;
  for (int kt = 0; kt < nkt; ++kt) {
    // stage K tile (64 keys x 128 d) and V^T tile (128 d x 64 keys)
    #pragma unroll
    for (int r = 0; r < 4; ++r) {
      int c = t + r * 256;
      { int i = c >> 4, dc = c & 15;
        *(uint4*)(&Ksm[i * 128 + dc * 8]) =
            *(const uint4*)(k + ((size_t)(b * S_LEN + kt * 64 + i)) * (NKV * HD) + kvh * HD + dc * 8); }
      { int d = c >> 3, kc2 = c & 7;
        *(uint4*)(&Vsm[d * 64 + kc2 * 8]) =
            *(const uint4*)(vT + ((size_t)((b * NKV + kvh) * HD + d)) * S_LEN + kt * 64 + kc2 * 8); }
    }
    __syncthreads();

    // S = Q K^T (C-layout: row = quad*4+r, col = key within 16-tile)
    float p[4][4];  // [nt][r]
    #pragma unroll
    for (int nt = 0; nt < 4; nt++) {
      f32x4 s_acc = (f32x4){0.f, 0.f, 0.f, 0.f};
      #pragma unroll
      for (int kc = 0; kc < 4; kc++) {
        bf16x8 kf = *(const bf16x8*)(&Ksm[(nt * 16 + col) * 128 + kc * 32 + quad * 8]);
        s_acc = __builtin_amdgcn_mfma_f32_16x16x32_bf16(qf[kc], kf, s_acc, 0, 0, 0);
      }
      #pragma unroll
      for (int r = 0; r < 4; r++) p[nt][r] = s_acc[r] * scale;
    }
    if (kt == nkt - 1) {  // only the diagonal tile needs the causal mask
      #pragma unroll
      for (int nt = 0; nt < 4; nt++) {
        int key = kt * 64 + nt * 16 + col;
        #pragma unroll
        for (int r = 0; r < 4; r++) {
          int rg = qrow + quad * 4 + r;
          if (key > rg) p[nt][r] = -1e30f;
        }
      }
    }
    // online softmax over this 64-key tile
    float mnew[4], alpha[4];
    #pragma unroll
    for (int r = 0; r < 4; r++) {
      float mx = fmaxf(fmaxf(p[0][r], p[1][r]), fmaxf(p[2][r], p[3][r]));
      mx = fmaxf(mx, __shfl_xor(mx, 1));
      mx = fmaxf(mx, __shfl_xor(mx, 2));
      mx = fmaxf(mx, __shfl_xor(mx, 4));
      mx = fmaxf(mx, __shfl_xor(mx, 8));
      mnew[r] = fmaxf(m_i[r], mx);
      alpha[r] = __expf(m_i[r] - mnew[r]);
      m_i[r] = mnew[r];
    }
    float rsum[4] = {0.f, 0.f, 0.f, 0.f};
    #pragma unroll
    for (int nt = 0; nt < 4; nt++)
      #pragma unroll
      for (int r = 0; r < 4; r++) {
        float e = __expf(p[nt][r] - mnew[r]);
        p[nt][r] = e;
        rsum[r] += e;
      }
    #pragma unroll
    for (int r = 0; r < 4; r++) {
      float rs = rsum[r];
      rs += __shfl_xor(rs, 1);
      rs += __shfl_xor(rs, 2);
      rs += __shfl_xor(rs, 4);
      rs += __shfl_xor(rs, 8);
      l_i[r] = l_i[r] * alpha[r] + rs;
    }
    #pragma unroll
    for (int dt = 0; dt < 8; dt++)
      #pragma unroll
      for (int r = 0; r < 4; r++) o[dt][r] *= alpha[r];

    // P: C-layout -> A-layout via wave-private LDS round trip
    #pragma unroll
    for (int nt = 0; nt < 4; nt++)
      #pragma unroll
      for (int r = 0; r < 4; r++)
        Psm[w][(quad * 4 + r) * 64 + nt * 16 + col] = f2bf(p[nt][r]);
    asm volatile("s_waitcnt lgkmcnt(0)" ::: "memory");  // wave-internal RAW on LDS
    bf16x8 pf[2];
    #pragma unroll
    for (int kc2 = 0; kc2 < 2; kc2++)
      pf[kc2] = *(const bf16x8*)(&Psm[w][col * 64 + kc2 * 32 + quad * 8]);

    // O += P V
    #pragma unroll
    for (int dt = 0; dt < 8; dt++) {
      #pragma unroll
      for (int kc2 = 0; kc2 < 2; kc2++) {
        bf16x8 vf = *(const bf16x8*)(&Vsm[(dt * 16 + col) * 64 + kc2 * 32 + quad * 8]);
        o[dt] = __builtin_amdgcn_mfma_f32_16x16x32_bf16(pf[kc2], vf, o[dt], 0, 0, 0);
      }
    }
    __syncthreads();
  }

  #pragma unroll
  for (int dt = 0; dt < 8; dt++) {
    int dcol = h * HD + dt * 16 + col;
    #pragma unroll
    for (int r = 0; r < 4; r++) {
      int rg = qrow + quad * 4 + r;
      ao[((size_t)(b * S_LEN) + rg) * DIM_ + dcol] = f2bf(o[dt][r] / l_i[r]);
    }
  }
}

extern "C" void kernel_launch(void* const* d_in, const int* in_sizes, int n_in,
                              void* d_out, int out_size, void* d_ws, size_t ws_size,
                              hipStream_t stream) {
  const float* x  = (const float*)d_in[0];
  const float* fc = (const float*)d_in[1];
  const float* fs = (const float*)d_in[2];
  const float* wq = (const float*)d_in[3];
  const float* wk = (const float*)d_in[4];
  const float* wv = (const float*)d_in[5];
  const float* wo = (const float*)d_in[6];
  float* out = (float*)d_out;

  char* ws = (char*)d_ws;
  unsigned short* xb  = (unsigned short*)(ws + 0);          // 4096x2048 bf16  (16 MiB)
  unsigned short* wqT = (unsigned short*)(ws + 16777216);   // 2048x2048       (8 MiB)
  unsigned short* wkT = (unsigned short*)(ws + 25165824);   // 1024x2048       (4 MiB)
  unsigned short* wvT = (unsigned short*)(ws + 29360128);   // 1024x2048       (4 MiB)
  unsigned short* woT = (unsigned short*)(ws + 33554432);   // 2048x2048       (8 MiB)
  unsigned short* qb  = (unsigned short*)(ws + 41943040);   // 4096x2048       (16 MiB)
  unsigned short* kb  = (unsigned short*)(ws + 58720256);   // 4096x1024       (8 MiB)
  unsigned short* vT  = (unsigned short*)(ws + 67108864);   // (b,kvh,d,s)     (8 MiB)
  unsigned short* ao  = (unsigned short*)(ws + 75497472);   // 4096x2048       (16 MiB)

  // convert x -> bf16
  k_f32_to_bf16<<<dim3((4096 * 2048 / 4) / 256), dim3(256), 0, stream>>>(x, xb, 4096 * 2048 / 4);
  // transpose-convert weights to (N, K) bf16
  k_transpose_bf16<<<dim3(64, 64), dim3(256), 0, stream>>>(wq, wqT, 2048, 2048);
  k_transpose_bf16<<<dim3(32, 64), dim3(256), 0, stream>>>(wk, wkT, 2048, 1024);
  k_transpose_bf16<<<dim3(32, 64), dim3(256), 0, stream>>>(wv, wvT, 2048, 1024);
  k_transpose_bf16<<<dim3(64, 64), dim3(256), 0, stream>>>(wo, woT, 2048, 2048);
  // projections
  k_gemm_bt<0><<<dim3(16, 32), dim3(256), 0, stream>>>(xb, wqT, (void*)qb, 2048, 2048);
  k_gemm_bt<0><<<dim3(8, 32),  dim3(256), 0, stream>>>(xb, wkT, (void*)kb, 1024, 2048);
  k_gemm_bt<2><<<dim3(8, 32),  dim3(256), 0, stream>>>(xb, wvT, (void*)vT, 1024, 2048);
  // RoPE on q and k (in place)
  k_rope<<<dim3(4, 4096), dim3(256), 0, stream>>>(qb, fc, fs, 2048);
  k_rope<<<dim3(2, 4096), dim3(256), 0, stream>>>(kb, fc, fs, 1024);
  // attention
  k_attn<<<dim3(32, 32), dim3(256), 0, stream>>>(qb, kb, vT, ao);
  // output projection (f32 out)
  k_gemm_bt<1><<<dim3(16, 32), dim3(256), 0, stream>>>(ao, woT, (void*)out, 2048, 2048);
}

// Round 2
// 469.208 us; speedup vs baseline: 1.3613x; 1.3613x over previous
//
#include <hip/hip_runtime.h>
#include <cstdint>
#include <cstddef>

#define S_LEN 2048
#define DIM_   2048
#define NH   16
#define NKV  8
#define HD   128

typedef __attribute__((ext_vector_type(8))) __bf16 bf16x8;
typedef __attribute__((ext_vector_type(4))) float  f32x4;

typedef const __attribute__((address_space(1))) void* gptr_t;
typedef __attribute__((address_space(3))) void*       sptr_t;

static __device__ __forceinline__ float bf2f(unsigned short u) {
  union { unsigned int i; float f; } v; v.i = ((unsigned int)u) << 16; return v.f;
}
static __device__ __forceinline__ unsigned short f2bf(float f) {
  union { float f; unsigned int i; } v; v.f = f;
  unsigned int u = v.i;
  unsigned int r = (u + 0x7FFFu + ((u >> 16) & 1u)) >> 16;
  return (unsigned short)r;
}

// ---------------- fp32 -> bf16 convert (vectorized) ----------------
__global__ void k_f32_to_bf16(const float* __restrict__ in, unsigned short* __restrict__ out, int n4) {
  int i = blockIdx.x * 256 + threadIdx.x;
  if (i >= n4) return;
  float4 v = ((const float4*)in)[i];
  ushort4 o; o.x = f2bf(v.x); o.y = f2bf(v.y); o.z = f2bf(v.z); o.w = f2bf(v.w);
  ((ushort4*)out)[i] = o;
}

// ------------- transpose + convert: w(K,N) f32 -> wt(N,K) bf16 -------------
__global__ void k_transpose_bf16(const float* __restrict__ w, unsigned short* __restrict__ wt,
                                 int K, int N) {
  __shared__ float tile[32][33];
  int lx = threadIdx.x & 31, ly = threadIdx.x >> 5; // 32 x 8
  int r0 = blockIdx.y * 32, c0 = blockIdx.x * 32;
  #pragma unroll
  for (int r = 0; r < 32; r += 8)
    tile[ly + r][lx] = w[(size_t)(r0 + ly + r) * N + c0 + lx];
  __syncthreads();
  #pragma unroll
  for (int r = 0; r < 32; r += 8)
    wt[(size_t)(c0 + ly + r) * K + r0 + lx] = f2bf(tile[lx][ly + r]);
}

// ------------- GEMM: C(MxN) = A(MxK) * BT(NxK)^T, bf16 in, fp32 acc -------------
// MODE 0: store bf16 natural C[m][n]
// MODE 1: store f32  natural C[m][n]
// MODE 2: store bf16 V-transposed: vT[(b*NKV+kvh)*HD + d][s]  (n = kvh*HD+d, m = b*S+s)
template<int MODE>
__global__ __launch_bounds__(256) void k_gemm_bt(
    const unsigned short* __restrict__ A, const unsigned short* __restrict__ BT,
    void* __restrict__ C, int N, int K) {
  __shared__ __align__(16) unsigned short Asm[128 * 32];
  __shared__ __align__(16) unsigned short Bsm[128 * 32];
  const int t = threadIdx.x;
  const int lane = t & 63, w = t >> 6;
  const int wm = (w >> 1) * 64, wn = (w & 1) * 64;
  const int col = lane & 15, quad = lane >> 4;
  const int m0 = blockIdx.y * 128, n0 = blockIdx.x * 128;

  f32x4 acc[4][4];
  #pragma unroll
  for (int i = 0; i < 4; i++)
    #pragma unroll
    for (int j = 0; j < 4; j++) acc[i][j] = (f32x4){0.f, 0.f, 0.f, 0.f};

  for (int kk = 0; kk < K; kk += 32) {
    // async global->LDS staging, width 16. LDS dest = wave-uniform base + lane*16:
    // byte addr of chunk c is exactly c*16, and c = (wave base) + lane.
    #pragma unroll
    for (int r = 0; r < 2; ++r) {
      int c = t + r * 256;
      int c0 = (t & ~63) + r * 256;  // wave-uniform chunk base
      const unsigned short* gA = A + (size_t)(m0 + (c >> 2)) * K + kk + (c & 3) * 8;
      const unsigned short* gB = BT + (size_t)(n0 + (c >> 2)) * K + kk + (c & 3) * 8;
      __builtin_amdgcn_global_load_lds((gptr_t)gA, (sptr_t)(&Asm[c0 * 8]), 16, 0, 0);
      __builtin_amdgcn_global_load_lds((gptr_t)gB, (sptr_t)(&Bsm[c0 * 8]), 16, 0, 0);
    }
    __syncthreads();
    bf16x8 af[4], bf[4];
    #pragma unroll
    for (int mi = 0; mi < 4; mi++) af[mi] = *(const bf16x8*)(&Asm[(wm + mi * 16 + col) * 32 + quad * 8]);
    #pragma unroll
    for (int ni = 0; ni < 4; ni++) bf[ni] = *(const bf16x8*)(&Bsm[(wn + ni * 16 + col) * 32 + quad * 8]);
    #pragma unroll
    for (int mi = 0; mi < 4; mi++)
      #pragma unroll
      for (int ni = 0; ni < 4; ni++)
        acc[mi][ni] = __builtin_amdgcn_mfma_f32_16x16x32_bf16(af[mi], bf[ni], acc[mi][ni], 0, 0, 0);
    __syncthreads();
  }

  #pragma unroll
  for (int mi = 0; mi < 4; mi++) {
    int row_base = m0 + wm + mi * 16 + quad * 4;
    #pragma unroll
    for (int ni = 0; ni < 4; ni++) {
      int col_g = n0 + wn + ni * 16 + col;
      if (MODE == 0) {
        unsigned short* O = (unsigned short*)C;
        #pragma unroll
        for (int r = 0; r < 4; r++) O[(size_t)(row_base + r) * N + col_g] = f2bf(acc[mi][ni][r]);
      } else if (MODE == 1) {
        float* O = (float*)C;
        #pragma unroll
        for (int r = 0; r < 4; r++) O[(size_t)(row_base + r) * N + col_g] = acc[mi][ni][r];
      } else {
        unsigned short* O = (unsigned short*)C;
        int b = row_base >> 11, s = row_base & (S_LEN - 1);
        int kvh = col_g >> 7, d = col_g & (HD - 1);
        ushort4 o4;
        o4.x = f2bf(acc[mi][ni][0]); o4.y = f2bf(acc[mi][ni][1]);
        o4.z = f2bf(acc[mi][ni][2]); o4.w = f2bf(acc[mi][ni][3]);
        *(ushort4*)(&O[((size_t)((b * NKV + kvh) * HD + d)) * S_LEN + s]) = o4;
      }
    }
  }
}

// ---------------- RoPE (in-place on bf16, pair = adjacent cols) ----------------
__global__ void k_rope(unsigned short* __restrict__ tq, const float* __restrict__ fc,
                       const float* __restrict__ fs, int ncols) {
  int p = blockIdx.x * 256 + threadIdx.x;  // pair index within a row
  int row = blockIdx.y;                    // 0..4095 (b*S+s)
  int half = ncols >> 1;
  if (p >= half) return;
  int s = row & (S_LEN - 1);
  int i = p & 63;  // (col % 128) / 2
  float c = fc[s * 64 + i], sn = fs[s * 64 + i];
  unsigned short* ptr = tq + (size_t)row * ncols + 2 * p;
  float p1 = bf2f(ptr[0]), p2 = bf2f(ptr[1]);
  ushort2 o; o.x = f2bf(p1 * c - p2 * sn); o.y = f2bf(p1 * sn + p2 * c);
  *(ushort2*)ptr = o;
}

// ---------------- Flash attention, causal, GQA (kvh = h>>1) ----------------
// q: (b,s,h,d) bf16 ld=2048 ; k: (b,s,kvh,d) bf16 ld=1024 ; vT: (b,kvh,d,s) bf16 ld=2048
// ao: (b,s,h,d) bf16 ld=2048
// Grid: x = bh (32), y = swizzled q-tile (32). Swizzle makes each CU's 4
// resident blocks sum to equal work (qt sets {j,15-j,16+j,31-j}).
// LDS rows padded +8 halfwords (16B) so row-to-row bank offset = 4 -> fragment
// reads hit the structural 8-dword/bank minimum instead of 16.
#define KLD 136   // 128 + 8
#define VLD 72    // 64 + 8
__global__ __launch_bounds__(256) void k_attn(
    const unsigned short* __restrict__ q, const unsigned short* __restrict__ k,
    const unsigned short* __restrict__ vT, unsigned short* __restrict__ ao) {
  __shared__ __align__(16) unsigned short Ksm[64 * KLD];   // P aliases into here after QK^T
  __shared__ __align__(16) unsigned short Vsm[128 * VLD];
  const int t = threadIdx.x;
  const int lane = t & 63, w = t >> 6;
  const int col = lane & 15, quad = lane >> 4;
  const int bh = blockIdx.x;
  const int b = bh >> 4, h = bh & 15, kvh = h >> 1;
  const int yy = blockIdx.y;
  const int kg = yy >> 3, jj = yy & 7;
  const int qt = (kg == 0) ? jj : (kg == 1) ? (15 - jj) : (kg == 2) ? (16 + jj) : (31 - jj);
  const int q0 = qt * 64;
  const int qrow = q0 + w * 16;  // this wave's 16 query rows start here
  unsigned short* Pw = &Ksm[w * 16 * VLD];  // wave-private P staging (4*16*72 <= 64*136)

  // Q fragments (A-operand layout), kept in registers for the whole block
  bf16x8 qf[4];
  const size_t qbase = ((size_t)(b * S_LEN) + qrow + col) * DIM_ + h * HD;
  #pragma unroll
  for (int kc = 0; kc < 4; kc++) qf[kc] = *(const bf16x8*)(q + qbase + kc * 32 + quad * 8);

  f32x4 o[8];
  #pragma unroll
  for (int i = 0; i < 8; i++) o[i] = (f32x4){0.f, 0.f, 0.f, 0.f};
  float m_i[4] = {-1e30f, -1e30f, -1e30f, -1e30f};
  float l_i[4] = {0.f, 0.f, 0.f, 0.f};
  const float scale = 0.08838834764831845f;  // 1/sqrt(128)

  const int nkt = qt + 1;
  for (int kt = 0; kt < nkt; ++kt) {
    // stage K tile (64 keys x 128 d) and V^T tile (128 d x 64 keys)
    #pragma unroll
    for (int r = 0; r < 4; ++r) {
      int c = t + r * 256;
      { int i = c >> 4, dc = c & 15;
        *(uint4*)(&Ksm[i * KLD + dc * 8]) =
            *(const uint4*)(k + ((size_t)(b * S_LEN + kt * 64 + i)) * (NKV * HD) + kvh * HD + dc * 8); }
      { int d = c >> 3, kc2 = c & 7;
        *(uint4*)(&Vsm[d * VLD + kc2 * 8]) =
            *(const uint4*)(vT + ((size_t)((b * NKV + kvh) * HD + d)) * S_LEN + kt * 64 + kc2 * 8); }
    }
    __syncthreads();

    // S = Q K^T (C-layout: row = quad*4+r, col = key within 16-tile)
    float p[4][4];  // [nt][r]
    #pragma unroll
    for (int nt = 0; nt < 4; nt++) {
      f32x4 s_acc = (f32x4){0.f, 0.f, 0.f, 0.f};
      #pragma unroll
      for (int kc = 0; kc < 4; kc++) {
        bf16x8 kf = *(const bf16x8*)(&Ksm[(nt * 16 + col) * KLD + kc * 32 + quad * 8]);
        s_acc = __builtin_amdgcn_mfma_f32_16x16x32_bf16(qf[kc], kf, s_acc, 0, 0, 0);
      }
      #pragma unroll
      for (int r = 0; r < 4; r++) p[nt][r] = s_acc[r] * scale;
    }
    if (kt == nkt - 1) {  // only the diagonal tile needs the causal mask
      #pragma unroll
      for (int nt = 0; nt < 4; nt++) {
        int key = kt * 64 + nt * 16 + col;
        #pragma unroll
        for (int r = 0; r < 4; r++) {
          int rg = qrow + quad * 4 + r;
          if (key > rg) p[nt][r] = -1e30f;
        }
      }
    }
    // online softmax over this 64-key tile
    float mnew[4], alpha[4];
    #pragma unroll
    for (int r = 0; r < 4; r++) {
      float mx = fmaxf(fmaxf(p[0][r], p[1][r]), fmaxf(p[2][r], p[3][r]));
      mx = fmaxf(mx, __shfl_xor(mx, 1));
      mx = fmaxf(mx, __shfl_xor(mx, 2));
      mx = fmaxf(mx, __shfl_xor(mx, 4));
      mx = fmaxf(mx, __shfl_xor(mx, 8));
      mnew[r] = fmaxf(m_i[r], mx);
      alpha[r] = __expf(m_i[r] - mnew[r]);
      m_i[r] = mnew[r];
    }
    float rsum[4] = {0.f, 0.f, 0.f, 0.f};
    #pragma unroll
    for (int nt = 0; nt < 4; nt++)
      #pragma unroll
      for (int r = 0; r < 4; r++) {
        float e = __expf(p[nt][r] - mnew[r]);
        p[nt][r] = e;
        rsum[r] += e;
      }
    #pragma unroll
    for (int r = 0; r < 4; r++) {
      float rs = rsum[r];
      rs += __shfl_xor(rs, 1);
      rs += __shfl_xor(rs, 2);
      rs += __shfl_xor(rs, 4);
      rs += __shfl_xor(rs, 8);
      l_i[r] = l_i[r] * alpha[r] + rs;
    }
    #pragma unroll
    for (int dt = 0; dt < 8; dt++)
      #pragma unroll
      for (int r = 0; r < 4; r++) o[dt][r] *= alpha[r];

    // all waves are done reading Ksm -> safe to overwrite with P
    __syncthreads();

    // P: C-layout -> A-layout via wave-private LDS round trip (aliased into Ksm)
    #pragma unroll
    for (int nt = 0; nt < 4; nt++)
      #pragma unroll
      for (int r = 0; r < 4; r++)
        Pw[(quad * 4 + r) * VLD + nt * 16 + col] = f2bf(p[nt][r]);
    asm volatile("s_waitcnt lgkmcnt(0)" ::: "memory");  // wave-internal RAW on LDS
    bf16x8 pf[2];
    #pragma unroll
    for (int kc2 = 0; kc2 < 2; kc2++)
      pf[kc2] = *(const bf16x8*)(&Pw[col * VLD + kc2 * 32 + quad * 8]);

    // O += P V
    #pragma unroll
    for (int dt = 0; dt < 8; dt++) {
      #pragma unroll
      for (int kc2 = 0; kc2 < 2; kc2++) {
        bf16x8 vf = *(const bf16x8*)(&Vsm[(dt * 16 + col) * VLD + kc2 * 32 + quad * 8]);
        o[dt] = __builtin_amdgcn_mfma_f32_16x16x32_bf16(pf[kc2], vf, o[dt], 0, 0, 0);
      }
    }
    __syncthreads();
  }

  #pragma unroll
  for (int dt = 0; dt < 8; dt++) {
    int dcol = h * HD + dt * 16 + col;
    #pragma unroll
    for (int r = 0; r < 4; r++) {
      int rg = qrow + quad * 4 + r;
      ao[((size_t)(b * S_LEN) + rg) * DIM_ + dcol] = f2bf(o[dt][r] / l_i[r]);
    }
  }
}

extern "C" void kernel_launch(void* const* d_in, const int* in_sizes, int n_in,
                              void* d_out, int out_size, void* d_ws, size_t ws_size,
                              hipStream_t stream) {
  const float* x  = (const float*)d_in[0];
  const float* fc = (const float*)d_in[1];
  const float* fs = (const float*)d_in[2];
  const float* wq = (const float*)d_in[3];
  const float* wk = (const float*)d_in[4];
  const float* wv = (const float*)d_in[5];
  const float* wo = (const float*)d_in[6];
  float* out = (float*)d_out;

  char* ws = (char*)d_ws;
  unsigned short* xb  = (unsigned short*)(ws + 0);          // 4096x2048 bf16  (16 MiB)
  unsigned short* wqT = (unsigned short*)(ws + 16777216);   // 2048x2048       (8 MiB)
  unsigned short* wkT = (unsigned short*)(ws + 25165824);   // 1024x2048       (4 MiB)
  unsigned short* wvT = (unsigned short*)(ws + 29360128);   // 1024x2048       (4 MiB)
  unsigned short* woT = (unsigned short*)(ws + 33554432);   // 2048x2048       (8 MiB)
  unsigned short* qb  = (unsigned short*)(ws + 41943040);   // 4096x2048       (16 MiB)
  unsigned short* kb  = (unsigned short*)(ws + 58720256);   // 4096x1024       (8 MiB)
  unsigned short* vT  = (unsigned short*)(ws + 67108864);   // (b,kvh,d,s)     (8 MiB)
  unsigned short* ao  = (unsigned short*)(ws + 75497472);   // 4096x2048       (16 MiB)

  // convert x -> bf16
  k_f32_to_bf16<<<dim3((4096 * 2048 / 4) / 256), dim3(256), 0, stream>>>(x, xb, 4096 * 2048 / 4);
  // transpose-convert weights to (N, K) bf16
  k_transpose_bf16<<<dim3(64, 64), dim3(256), 0, stream>>>(wq, wqT, 2048, 2048);
  k_transpose_bf16<<<dim3(32, 64), dim3(256), 0, stream>>>(wk, wkT, 2048, 1024);
  k_transpose_bf16<<<dim3(32, 64), dim3(256), 0, stream>>>(wv, wvT, 2048, 1024);
  k_transpose_bf16<<<dim3(64, 64), dim3(256), 0, stream>>>(wo, woT, 2048, 2048);
  // projections
  k_gemm_bt<0><<<dim3(16, 32), dim3(256), 0, stream>>>(xb, wqT, (void*)qb, 2048, 2048);
  k_gemm_bt<0><<<dim3(8, 32),  dim3(256), 0, stream>>>(xb, wkT, (void*)kb, 1024, 2048);
  k_gemm_bt<2><<<dim3(8, 32),  dim3(256), 0, stream>>>(xb, wvT, (void*)vT, 1024, 2048);
  // RoPE on q and k (in place)
  k_rope<<<dim3(4, 4096), dim3(256), 0, stream>>>(qb, fc, fs, 2048);
  k_rope<<<dim3(2, 4096), dim3(256), 0, stream>>>(kb, fc, fs, 1024);
  // attention (x = bh so CU-resident blocks get mixed q-tiles)
  k_attn<<<dim3(32, 32), dim3(256), 0, stream>>>(qb, kb, vT, ao);
  // output projection (f32 out)
  k_gemm_bt<1><<<dim3(16, 32), dim3(256), 0, stream>>>(ao, woT, (void*)out, 2048, 2048);
}

// Round 3
// 431.558 us; speedup vs baseline: 1.4801x; 1.0872x over previous
//
#include <hip/hip_runtime.h>
#include <cstdint>
#include <cstddef>

#define S_LEN 2048
#define DIM_   2048
#define NH   16
#define NKV  8
#define HD   128

typedef __attribute__((ext_vector_type(8))) __bf16 bf16x8;
typedef __attribute__((ext_vector_type(4))) float  f32x4;

typedef const __attribute__((address_space(1))) void* gptr_t;
typedef __attribute__((address_space(3))) void*       sptr_t;

static __device__ __forceinline__ float bf2f(unsigned short u) {
  union { unsigned int i; float f; } v; v.i = ((unsigned int)u) << 16; return v.f;
}
static __device__ __forceinline__ unsigned short f2bf(float f) {
  union { float f; unsigned int i; } v; v.f = f;
  unsigned int u = v.i;
  unsigned int r = (u + 0x7FFFu + ((u >> 16) & 1u)) >> 16;
  return (unsigned short)r;
}

// ---------------- fp32 -> bf16 convert (vectorized) ----------------
__global__ void k_f32_to_bf16(const float* __restrict__ in, unsigned short* __restrict__ out, int n4) {
  int i = blockIdx.x * 256 + threadIdx.x;
  if (i >= n4) return;
  float4 v = ((const float4*)in)[i];
  ushort4 o; o.x = f2bf(v.x); o.y = f2bf(v.y); o.z = f2bf(v.z); o.w = f2bf(v.w);
  ((ushort4*)out)[i] = o;
}

// ------------- transpose + convert: w(K,N) f32 -> wt(N,K) bf16 -------------
__global__ void k_transpose_bf16(const float* __restrict__ w, unsigned short* __restrict__ wt,
                                 int K, int N) {
  __shared__ float tile[32][33];
  int lx = threadIdx.x & 31, ly = threadIdx.x >> 5; // 32 x 8
  int r0 = blockIdx.y * 32, c0 = blockIdx.x * 32;
  #pragma unroll
  for (int r = 0; r < 32; r += 8)
    tile[ly + r][lx] = w[(size_t)(r0 + ly + r) * N + c0 + lx];
  __syncthreads();
  #pragma unroll
  for (int r = 0; r < 32; r += 8)
    wt[(size_t)(c0 + ly + r) * K + r0 + lx] = f2bf(tile[lx][ly + r]);
}

// ------------- GEMM: C(MxN) = A(MxK) * BT(NxK)^T, bf16 in, fp32 acc -------------
// MODE 1: store f32 natural C[m][n]
// MODE 3: fused QKV epilogue. N=4096: cols [0,2048)=q (+RoPE), [2048,3072)=k (+RoPE),
//         [3072,4096)=v stored transposed vT[(b*NKV+kvh)*HD+d][s].
template<int MODE>
__global__ __launch_bounds__(256) void k_gemm_bt(
    const unsigned short* __restrict__ A, const unsigned short* __restrict__ BT,
    void* __restrict__ C, int N, int K,
    const float* __restrict__ fc, const float* __restrict__ fs,
    unsigned short* __restrict__ kb, unsigned short* __restrict__ vb) {
  __shared__ __align__(16) unsigned short Asm[128 * 32];
  __shared__ __align__(16) unsigned short Bsm[128 * 32];
  const int t = threadIdx.x;
  const int lane = t & 63, w = t >> 6;
  const int wm = (w >> 1) * 64, wn = (w & 1) * 64;
  const int col = lane & 15, quad = lane >> 4;
  const int m0 = blockIdx.y * 128, n0 = blockIdx.x * 128;

  f32x4 acc[4][4];
  #pragma unroll
  for (int i = 0; i < 4; i++)
    #pragma unroll
    for (int j = 0; j < 4; j++) acc[i][j] = (f32x4){0.f, 0.f, 0.f, 0.f};

  for (int kk = 0; kk < K; kk += 32) {
    // async global->LDS staging, width 16 (dest = wave-uniform base + lane*16)
    #pragma unroll
    for (int r = 0; r < 2; ++r) {
      int c = t + r * 256;
      int c0 = (t & ~63) + r * 256;  // wave-uniform chunk base
      const unsigned short* gA = A + (size_t)(m0 + (c >> 2)) * K + kk + (c & 3) * 8;
      const unsigned short* gB = BT + (size_t)(n0 + (c >> 2)) * K + kk + (c & 3) * 8;
      __builtin_amdgcn_global_load_lds((gptr_t)gA, (sptr_t)(&Asm[c0 * 8]), 16, 0, 0);
      __builtin_amdgcn_global_load_lds((gptr_t)gB, (sptr_t)(&Bsm[c0 * 8]), 16, 0, 0);
    }
    __syncthreads();
    bf16x8 af[4], bf[4];
    #pragma unroll
    for (int mi = 0; mi < 4; mi++) af[mi] = *(const bf16x8*)(&Asm[(wm + mi * 16 + col) * 32 + quad * 8]);
    #pragma unroll
    for (int ni = 0; ni < 4; ni++) bf[ni] = *(const bf16x8*)(&Bsm[(wn + ni * 16 + col) * 32 + quad * 8]);
    #pragma unroll
    for (int mi = 0; mi < 4; mi++)
      #pragma unroll
      for (int ni = 0; ni < 4; ni++)
        acc[mi][ni] = __builtin_amdgcn_mfma_f32_16x16x32_bf16(af[mi], bf[ni], acc[mi][ni], 0, 0, 0);
    __syncthreads();
  }

  #pragma unroll
  for (int mi = 0; mi < 4; mi++) {
    int row_base = m0 + wm + mi * 16 + quad * 4;
    #pragma unroll
    for (int ni = 0; ni < 4; ni++) {
      int col_g = n0 + wn + ni * 16 + col;
      if (MODE == 1) {
        float* O = (float*)C;
        #pragma unroll
        for (int r = 0; r < 4; r++) O[(size_t)(row_base + r) * N + col_g] = acc[mi][ni][r];
      } else {  // MODE 3
        int region = col_g >> 10;  // 0,1: q ; 2: k ; 3: v
        if (region < 3) {
          // RoPE: pairs are adjacent d = adjacent lanes (col^1 = lane^1)
          int ri = (col_g & 127) >> 1;
          float sgn = (col_g & 1) ? 1.f : -1.f;
          unsigned short* qO = (unsigned short*)C;
          #pragma unroll
          for (int r = 0; r < 4; r++) {
            int row = row_base + r;
            int s = row & (S_LEN - 1);
            float cv = fc[s * 64 + ri], sv = fs[s * 64 + ri];
            float val = acc[mi][ni][r];
            float other = __shfl_xor(val, 1);
            float res = val * cv + sgn * other * sv;
            if (region < 2) qO[(size_t)row * 2048 + col_g] = f2bf(res);
            else            kb[(size_t)row * 1024 + (col_g - 2048)] = f2bf(res);
          }
        } else {
          int n_local = col_g - 3072;
          int b = row_base >> 11, s = row_base & (S_LEN - 1);
          int kvh = n_local >> 7, d = n_local & (HD - 1);
          ushort4 o4;
          o4.x = f2bf(acc[mi][ni][0]); o4.y = f2bf(acc[mi][ni][1]);
          o4.z = f2bf(acc[mi][ni][2]); o4.w = f2bf(acc[mi][ni][3]);
          *(ushort4*)(&vb[((size_t)((b * NKV + kvh) * HD + d)) * S_LEN + s]) = o4;
        }
      }
    }
  }
}

// ---------------- Flash attention, causal, GQA (kvh = h>>1) ----------------
// 512-thread blocks, 8 waves. Waves 0-3 own q-tile y, waves 4-7 own q-tile 31-y:
// every block does exactly (y+1)+(32-y)=33 compute-tiles sharing one K/V staging
// -> uniform block duration, zero structural tail. Grid (32 bh, 16 pairs) = 2 blocks/CU.
#define KLD 136   // 128 + 8 (pad: fragment reads hit the 8-dword/bank structural min)
#define VLD 72    // 64 + 8
__global__ __launch_bounds__(512) void k_attn(
    const unsigned short* __restrict__ q, const unsigned short* __restrict__ k,
    const unsigned short* __restrict__ vT, unsigned short* __restrict__ ao) {
  __shared__ __align__(16) unsigned short Ksm[64 * KLD];        // 17408 B
  __shared__ __align__(16) unsigned short Vsm[128 * VLD];       // 18432 B
  __shared__ __align__(16) unsigned short Psm[8 * 16 * VLD];    // 18432 B
  const int t = threadIdx.x;
  const int lane = t & 63, w = t >> 6;
  const int col = lane & 15, quad = lane >> 4;
  const int bh = blockIdx.x;
  const int b = bh >> 4, h = bh & 15, kvh = h >> 1;
  const int y = blockIdx.y;                   // 0..15
  const int my_qt = (w < 4) ? y : (31 - y);
  const int qrow = my_qt * 64 + (w & 3) * 16; // this wave's 16 query rows
  unsigned short* Pw = &Psm[w * 16 * VLD];

  // Q fragments (A-operand layout), registers for the whole block
  bf16x8 qf[4];
  const size_t qbase = ((size_t)(b * S_LEN) + qrow + col) * DIM_ + h * HD;
  #pragma unroll
  for (int kc = 0; kc < 4; kc++) qf[kc] = *(const bf16x8*)(q + qbase + kc * 32 + quad * 8);

  f32x4 o[8];
  #pragma unroll
  for (int i = 0; i < 8; i++) o[i] = (f32x4){0.f, 0.f, 0.f, 0.f};
  float m_i[4] = {-1e30f, -1e30f, -1e30f, -1e30f};
  float l_i[4] = {0.f, 0.f, 0.f, 0.f};
  const float scale = 0.08838834764831845f;  // 1/sqrt(128)

  const int nkt = 32 - y;  // covers kt 0..31-y (enough for both halves)
  for (int kt = 0; kt < nkt; ++kt) {
    // stage K tile (64 keys x 128 d) and V^T tile (128 d x 64 keys), 512 threads
    #pragma unroll
    for (int r = 0; r < 2; ++r) {
      int c = t + r * 512;
      { int i = c >> 4, dc = c & 15;
        *(uint4*)(&Ksm[i * KLD + dc * 8]) =
            *(const uint4*)(k + ((size_t)(b * S_LEN + kt * 64 + i)) * (NKV * HD) + kvh * HD + dc * 8); }
      { int d = c >> 3, kc2 = c & 7;
        *(uint4*)(&Vsm[d * VLD + kc2 * 8]) =
            *(const uint4*)(vT + ((size_t)((b * NKV + kvh) * HD + d)) * S_LEN + kt * 64 + kc2 * 8); }
    }
    __syncthreads();

    if (kt <= my_qt) {  // wave-uniform: this wave's causal range
      // S = Q K^T (C-layout: row = quad*4+r, col = key within 16-tile)
      float p[4][4];  // [nt][r]
      #pragma unroll
      for (int nt = 0; nt < 4; nt++) {
        f32x4 s_acc = (f32x4){0.f, 0.f, 0.f, 0.f};
        #pragma unroll
        for (int kc = 0; kc < 4; kc++) {
          bf16x8 kf = *(const bf16x8*)(&Ksm[(nt * 16 + col) * KLD + kc * 32 + quad * 8]);
          s_acc = __builtin_amdgcn_mfma_f32_16x16x32_bf16(qf[kc], kf, s_acc, 0, 0, 0);
        }
        #pragma unroll
        for (int r = 0; r < 4; r++) p[nt][r] = s_acc[r] * scale;
      }
      if (kt == my_qt) {  // diagonal tile: causal mask
        #pragma unroll
        for (int nt = 0; nt < 4; nt++) {
          int key = kt * 64 + nt * 16 + col;
          #pragma unroll
          for (int r = 0; r < 4; r++) {
            int rg = qrow + quad * 4 + r;
            if (key > rg) p[nt][r] = -1e30f;
          }
        }
      }
      // online softmax over this 64-key tile
      float mnew[4], alpha[4];
      #pragma unroll
      for (int r = 0; r < 4; r++) {
        float mx = fmaxf(fmaxf(p[0][r], p[1][r]), fmaxf(p[2][r], p[3][r]));
        mx = fmaxf(mx, __shfl_xor(mx, 1));
        mx = fmaxf(mx, __shfl_xor(mx, 2));
        mx = fmaxf(mx, __shfl_xor(mx, 4));
        mx = fmaxf(mx, __shfl_xor(mx, 8));
        mnew[r] = fmaxf(m_i[r], mx);
        alpha[r] = __expf(m_i[r] - mnew[r]);
        m_i[r] = mnew[r];
      }
      float rsum[4] = {0.f, 0.f, 0.f, 0.f};
      #pragma unroll
      for (int nt = 0; nt < 4; nt++)
        #pragma unroll
        for (int r = 0; r < 4; r++) {
          float e = __expf(p[nt][r] - mnew[r]);
          p[nt][r] = e;
          rsum[r] += e;
        }
      #pragma unroll
      for (int r = 0; r < 4; r++) {
        float rs = rsum[r];
        rs += __shfl_xor(rs, 1);
        rs += __shfl_xor(rs, 2);
        rs += __shfl_xor(rs, 4);
        rs += __shfl_xor(rs, 8);
        l_i[r] = l_i[r] * alpha[r] + rs;
      }
      #pragma unroll
      for (int dt = 0; dt < 8; dt++)
        #pragma unroll
        for (int r = 0; r < 4; r++) o[dt][r] *= alpha[r];

      // P: C-layout -> A-layout via wave-private LDS round trip
      #pragma unroll
      for (int nt = 0; nt < 4; nt++)
        #pragma unroll
        for (int r = 0; r < 4; r++)
          Pw[(quad * 4 + r) * VLD + nt * 16 + col] = f2bf(p[nt][r]);
      asm volatile("s_waitcnt lgkmcnt(0)" ::: "memory");  // wave-internal RAW on LDS
      bf16x8 pf[2];
      #pragma unroll
      for (int kc2 = 0; kc2 < 2; kc2++)
        pf[kc2] = *(const bf16x8*)(&Pw[col * VLD + kc2 * 32 + quad * 8]);

      // O += P V
      #pragma unroll
      for (int dt = 0; dt < 8; dt++) {
        #pragma unroll
        for (int kc2 = 0; kc2 < 2; kc2++) {
          bf16x8 vf = *(const bf16x8*)(&Vsm[(dt * 16 + col) * VLD + kc2 * 32 + quad * 8]);
          o[dt] = __builtin_amdgcn_mfma_f32_16x16x32_bf16(pf[kc2], vf, o[dt], 0, 0, 0);
        }
      }
    }
    __syncthreads();
  }

  #pragma unroll
  for (int dt = 0; dt < 8; dt++) {
    int dcol = h * HD + dt * 16 + col;
    #pragma unroll
    for (int r = 0; r < 4; r++) {
      int rg = qrow + quad * 4 + r;
      ao[((size_t)(b * S_LEN) + rg) * DIM_ + dcol] = f2bf(o[dt][r] / l_i[r]);
    }
  }
}

extern "C" void kernel_launch(void* const* d_in, const int* in_sizes, int n_in,
                              void* d_out, int out_size, void* d_ws, size_t ws_size,
                              hipStream_t stream) {
  const float* x  = (const float*)d_in[0];
  const float* fc = (const float*)d_in[1];
  const float* fs = (const float*)d_in[2];
  const float* wq = (const float*)d_in[3];
  const float* wk = (const float*)d_in[4];
  const float* wv = (const float*)d_in[5];
  const float* wo = (const float*)d_in[6];
  float* out = (float*)d_out;

  char* ws = (char*)d_ws;
  const size_t MB = 1024 * 1024;
  unsigned short* xb    = (unsigned short*)(ws + 0 * MB);    // 4096x2048 bf16 (16 MiB)
  unsigned short* wqkvT = (unsigned short*)(ws + 16 * MB);   // 4096x2048      (16 MiB)
  unsigned short* woT   = (unsigned short*)(ws + 32 * MB);   // 2048x2048      (8 MiB)
  unsigned short* qb    = (unsigned short*)(ws + 40 * MB);   // 4096x2048      (16 MiB)
  unsigned short* kb    = (unsigned short*)(ws + 56 * MB);   // 4096x1024      (8 MiB)
  unsigned short* vT    = (unsigned short*)(ws + 64 * MB);   // (b,kvh,d,s)    (8 MiB)
  unsigned short* ao    = (unsigned short*)(ws + 72 * MB);   // 4096x2048      (16 MiB)

  // convert x -> bf16
  k_f32_to_bf16<<<dim3((4096 * 2048 / 4) / 256), dim3(256), 0, stream>>>(x, xb, 4096 * 2048 / 4);
  // transpose-convert weights: wq|wk|wv stacked into wqkvT (rows 0..4095), wo -> woT
  k_transpose_bf16<<<dim3(64, 64), dim3(256), 0, stream>>>(wq, wqkvT, 2048, 2048);
  k_transpose_bf16<<<dim3(32, 64), dim3(256), 0, stream>>>(wk, wqkvT + (size_t)2048 * 2048, 2048, 1024);
  k_transpose_bf16<<<dim3(32, 64), dim3(256), 0, stream>>>(wv, wqkvT + (size_t)3072 * 2048, 2048, 1024);
  k_transpose_bf16<<<dim3(64, 64), dim3(256), 0, stream>>>(wo, woT, 2048, 2048);
  // fused QKV projection + RoPE + V transpose (one dispatch, 1024 blocks)
  k_gemm_bt<3><<<dim3(32, 32), dim3(256), 0, stream>>>(xb, wqkvT, (void*)qb, 4096, 2048, fc, fs, kb, vT);
  // attention
  k_attn<<<dim3(32, 16), dim3(512), 0, stream>>>(qb, kb, vT, ao);
  // output projection (f32 out)
  k_gemm_bt<1><<<dim3(16, 32), dim3(256), 0, stream>>>(ao, woT, (void*)out, 2048, 2048, nullptr, nullptr, nullptr, nullptr);
}

// Round 4
// 403.644 us; speedup vs baseline: 1.5824x; 1.0692x over previous
//
#include <hip/hip_runtime.h>
#include <cstdint>
#include <cstddef>

#define S_LEN 2048
#define DIM_   2048
#define NH   16
#define NKV  8
#define HD   128

typedef __attribute__((ext_vector_type(8))) __bf16 bf16x8;
typedef __attribute__((ext_vector_type(4))) float  f32x4;

typedef const __attribute__((address_space(1))) void* gptr_t;
typedef __attribute__((address_space(3))) void*       sptr_t;

static __device__ __forceinline__ float bf2f(unsigned short u) {
  union { unsigned int i; float f; } v; v.i = ((unsigned int)u) << 16; return v.f;
}
static __device__ __forceinline__ unsigned short f2bf(float f) {
  union { float f; unsigned int i; } v; v.f = f;
  unsigned int u = v.i;
  unsigned int r = (u + 0x7FFFu + ((u >> 16) & 1u)) >> 16;
  return (unsigned short)r;
}

// scale(1/sqrt(128)) * log2(e) — folded into q so softmax uses exp2 directly
#define QSCALE 0.12751744f

// ---------------- prep: x->bf16 convert + 4 weight transpose-converts ----------------
// blocks [0,8192): convert (1024 f32 each)
// [8192,12288): wq->wqkvT rows 0..2047     (64x64 tiles)
// [12288,14336): wk->wqkvT rows 2048..3071 (32x64)
// [14336,16384): wv->wqkvT rows 3072..4095 (32x64)
// [16384,20480): wo->woT                   (64x64)
__global__ void k_prep(const float* __restrict__ x, unsigned short* __restrict__ xb,
                       const float* __restrict__ wq, const float* __restrict__ wk,
                       const float* __restrict__ wv, const float* __restrict__ wo,
                       unsigned short* __restrict__ wqkvT, unsigned short* __restrict__ woT) {
  int bid = blockIdx.x;
  if (bid < 8192) {
    int i = bid * 256 + threadIdx.x;
    float4 v = ((const float4*)x)[i];
    ushort4 o; o.x = f2bf(v.x); o.y = f2bf(v.y); o.z = f2bf(v.z); o.w = f2bf(v.w);
    ((ushort4*)xb)[i] = o;
    return;
  }
  bid -= 8192;
  const float* src; unsigned short* dst; int N, ntx;
  if (bid < 4096)      { src = wq; dst = wqkvT;                       N = 2048; ntx = 64; }
  else if (bid < 6144) { bid -= 4096; src = wk; dst = wqkvT + (size_t)2048 * 2048; N = 1024; ntx = 32; }
  else if (bid < 8192) { bid -= 6144; src = wv; dst = wqkvT + (size_t)3072 * 2048; N = 1024; ntx = 32; }
  else                 { bid -= 8192; src = wo; dst = woT;            N = 2048; ntx = 64; }
  const int K = 2048;
  __shared__ float tile[32][33];
  int lx = threadIdx.x & 31, ly = threadIdx.x >> 5; // 32 x 8
  int r0 = (bid / ntx) * 32, c0 = (bid % ntx) * 32;
  #pragma unroll
  for (int r = 0; r < 32; r += 8)
    tile[ly + r][lx] = src[(size_t)(r0 + ly + r) * N + c0 + lx];
  __syncthreads();
  #pragma unroll
  for (int r = 0; r < 32; r += 8)
    dst[(size_t)(c0 + ly + r) * K + r0 + lx] = f2bf(tile[lx][ly + r]);
}

// ------------- GEMM: C(MxN) = A(MxK) * BT(NxK)^T, bf16 in, fp32 acc -------------
// BK=64, XOR-swizzled LDS via source permutation: LDS slot c (16B chunks, 8/row)
// holds global chunk (c&7)^(row&7) -> fragment reads cover all 32 banks (2-way = free)
// while global_load_lds keeps its mandatory dest = wave-base + lane*16 layout.
// MODE 1: store f32 natural C[m][n]
// MODE 3: fused QKV epilogue. N=4096: cols [0,2048)=q (+RoPE, *QSCALE),
//         [2048,3072)=k (+RoPE), [3072,4096)=v stored transposed vT[(b*8+kvh)*128+d][s].
template<int MODE>
__global__ __launch_bounds__(256) void k_gemm_bt(
    const unsigned short* __restrict__ A, const unsigned short* __restrict__ BT,
    void* __restrict__ C, int N, int K,
    const float* __restrict__ fc, const float* __restrict__ fs,
    unsigned short* __restrict__ kb, unsigned short* __restrict__ vb) {
  __shared__ __align__(16) unsigned short Asm[128 * 64];
  __shared__ __align__(16) unsigned short Bsm[128 * 64];
  const int t = threadIdx.x;
  const int lane = t & 63, w = t >> 6;
  const int wm = (w >> 1) * 64, wn = (w & 1) * 64;
  const int col = lane & 15, quad = lane >> 4;
  const int m0 = blockIdx.y * 128, n0 = blockIdx.x * 128;

  f32x4 acc[4][4];
  #pragma unroll
  for (int i = 0; i < 4; i++)
    #pragma unroll
    for (int j = 0; j < 4; j++) acc[i][j] = (f32x4){0.f, 0.f, 0.f, 0.f};

  for (int kk = 0; kk < K; kk += 64) {
    // stage 128x64 A and B tiles: 1024 chunks each, 4 per thread per matrix
    #pragma unroll
    for (int r = 0; r < 4; ++r) {
      int c = t + r * 256;
      int c0 = (t & ~63) + r * 256;   // wave-uniform chunk base
      int row = c >> 3;
      int kcs = (c & 7) ^ (row & 7);  // source permutation = target swizzle
      const unsigned short* gA = A + (size_t)(m0 + row) * K + kk + kcs * 8;
      const unsigned short* gB = BT + (size_t)(n0 + row) * K + kk + kcs * 8;
      __builtin_amdgcn_global_load_lds((gptr_t)gA, (sptr_t)(&Asm[c0 * 8]), 16, 0, 0);
      __builtin_amdgcn_global_load_lds((gptr_t)gB, (sptr_t)(&Bsm[c0 * 8]), 16, 0, 0);
    }
    __syncthreads();
    #pragma unroll
    for (int kc2 = 0; kc2 < 2; kc2++) {
      bf16x8 af[4], bf[4];
      #pragma unroll
      for (int mi = 0; mi < 4; mi++) {
        int rowA = wm + mi * 16 + col;
        af[mi] = *(const bf16x8*)(&Asm[rowA * 64 + (((kc2 * 4 + quad) ^ (col & 7)) * 8)]);
      }
      #pragma unroll
      for (int ni = 0; ni < 4; ni++) {
        int rowB = wn + ni * 16 + col;
        bf[ni] = *(const bf16x8*)(&Bsm[rowB * 64 + (((kc2 * 4 + quad) ^ (col & 7)) * 8)]);
      }
      #pragma unroll
      for (int mi = 0; mi < 4; mi++)
        #pragma unroll
        for (int ni = 0; ni < 4; ni++)
          acc[mi][ni] = __builtin_amdgcn_mfma_f32_16x16x32_bf16(af[mi], bf[ni], acc[mi][ni], 0, 0, 0);
    }
    __syncthreads();
  }

  #pragma unroll
  for (int mi = 0; mi < 4; mi++) {
    int row_base = m0 + wm + mi * 16 + quad * 4;
    #pragma unroll
    for (int ni = 0; ni < 4; ni++) {
      int col_g = n0 + wn + ni * 16 + col;
      if (MODE == 1) {
        float* O = (float*)C;
        #pragma unroll
        for (int r = 0; r < 4; r++) O[(size_t)(row_base + r) * N + col_g] = acc[mi][ni][r];
      } else {  // MODE 3
        int region = col_g >> 10;  // 0,1: q ; 2: k ; 3: v
        if (region < 3) {
          // RoPE: pairs are adjacent d = adjacent lanes (col^1 = lane^1)
          int ri = (col_g & 127) >> 1;
          float sgn = (col_g & 1) ? 1.f : -1.f;
          unsigned short* qO = (unsigned short*)C;
          #pragma unroll
          for (int r = 0; r < 4; r++) {
            int row = row_base + r;
            int s = row & (S_LEN - 1);
            float cv = fc[s * 64 + ri], sv = fs[s * 64 + ri];
            float val = acc[mi][ni][r];
            float other = __shfl_xor(val, 1);
            float res = val * cv + sgn * other * sv;
            if (region < 2) qO[(size_t)row * 2048 + col_g] = f2bf(res * QSCALE);
            else            kb[(size_t)row * 1024 + (col_g - 2048)] = f2bf(res);
          }
        } else {
          int n_local = col_g - 3072;
          int b = row_base >> 11, s = row_base & (S_LEN - 1);
          int kvh = n_local >> 7, d = n_local & (HD - 1);
          ushort4 o4;
          o4.x = f2bf(acc[mi][ni][0]); o4.y = f2bf(acc[mi][ni][1]);
          o4.z = f2bf(acc[mi][ni][2]); o4.w = f2bf(acc[mi][ni][3]);
          *(ushort4*)(&vb[((size_t)((b * NKV + kvh) * HD + d)) * S_LEN + s]) = o4;
        }
      }
    }
  }
}

// ---------------- Flash attention, causal, GQA (kvh = h>>1) ----------------
// 512-thread blocks, 8 waves. Waves 0-3 own q-tile y, waves 4-7 own 31-y:
// every block does exactly 33 compute-tiles sharing one K/V staging.
// q is pre-scaled by scale*log2e -> softmax uses exp2f (single v_exp_f32).
#define KLD 136   // 128 + 8
#define VLD 72    // 64 + 8
__global__ __launch_bounds__(512) void k_attn(
    const unsigned short* __restrict__ q, const unsigned short* __restrict__ k,
    const unsigned short* __restrict__ vT, unsigned short* __restrict__ ao) {
  __shared__ __align__(16) unsigned short Ksm[64 * KLD];
  __shared__ __align__(16) unsigned short Vsm[128 * VLD];
  __shared__ __align__(16) unsigned short Psm[8 * 16 * VLD];
  const int t = threadIdx.x;
  const int lane = t & 63, w = t >> 6;
  const int col = lane & 15, quad = lane >> 4;
  const int bh = blockIdx.x;
  const int b = bh >> 4, h = bh & 15, kvh = h >> 1;
  const int y = blockIdx.y;                   // 0..15
  const int my_qt = (w < 4) ? y : (31 - y);
  const int qrow = my_qt * 64 + (w & 3) * 16;
  unsigned short* Pw = &Psm[w * 16 * VLD];

  bf16x8 qf[4];
  const size_t qbase = ((size_t)(b * S_LEN) + qrow + col) * DIM_ + h * HD;
  #pragma unroll
  for (int kc = 0; kc < 4; kc++) qf[kc] = *(const bf16x8*)(q + qbase + kc * 32 + quad * 8);

  f32x4 o[8];
  #pragma unroll
  for (int i = 0; i < 8; i++) o[i] = (f32x4){0.f, 0.f, 0.f, 0.f};
  float m_i[4] = {-1e30f, -1e30f, -1e30f, -1e30f};
  float l_i[4] = {0.f, 0.f, 0.f, 0.f};

  const int nkt = 32 - y;
  for (int kt = 0; kt < nkt; ++kt) {
    #pragma unroll
    for (int r = 0; r < 2; ++r) {
      int c = t + r * 512;
      { int i = c >> 4, dc = c & 15;
        *(uint4*)(&Ksm[i * KLD + dc * 8]) =
            *(const uint4*)(k + ((size_t)(b * S_LEN + kt * 64 + i)) * (NKV * HD) + kvh * HD + dc * 8); }
      { int d = c >> 3, kc2 = c & 7;
        *(uint4*)(&Vsm[d * VLD + kc2 * 8]) =
            *(const uint4*)(vT + ((size_t)((b * NKV + kvh) * HD + d)) * S_LEN + kt * 64 + kc2 * 8); }
    }
    __syncthreads();

    if (kt <= my_qt) {
      float p[4][4];
      #pragma unroll
      for (int nt = 0; nt < 4; nt++) {
        f32x4 s_acc = (f32x4){0.f, 0.f, 0.f, 0.f};
        #pragma unroll
        for (int kc = 0; kc < 4; kc++) {
          bf16x8 kf = *(const bf16x8*)(&Ksm[(nt * 16 + col) * KLD + kc * 32 + quad * 8]);
          s_acc = __builtin_amdgcn_mfma_f32_16x16x32_bf16(qf[kc], kf, s_acc, 0, 0, 0);
        }
        #pragma unroll
        for (int r = 0; r < 4; r++) p[nt][r] = s_acc[r];
      }
      if (kt == my_qt) {
        #pragma unroll
        for (int nt = 0; nt < 4; nt++) {
          int key = kt * 64 + nt * 16 + col;
          #pragma unroll
          for (int r = 0; r < 4; r++) {
            int rg = qrow + quad * 4 + r;
            if (key > rg) p[nt][r] = -1e30f;
          }
        }
      }
      float mnew[4], alpha[4];
      #pragma unroll
      for (int r = 0; r < 4; r++) {
        float mx = fmaxf(fmaxf(p[0][r], p[1][r]), fmaxf(p[2][r], p[3][r]));
        mx = fmaxf(mx, __shfl_xor(mx, 1));
        mx = fmaxf(mx, __shfl_xor(mx, 2));
        mx = fmaxf(mx, __shfl_xor(mx, 4));
        mx = fmaxf(mx, __shfl_xor(mx, 8));
        mnew[r] = fmaxf(m_i[r], mx);
        alpha[r] = exp2f(m_i[r] - mnew[r]);
        m_i[r] = mnew[r];
      }
      float rsum[4] = {0.f, 0.f, 0.f, 0.f};
      #pragma unroll
      for (int nt = 0; nt < 4; nt++)
        #pragma unroll
        for (int r = 0; r < 4; r++) {
          float e = exp2f(p[nt][r] - mnew[r]);
          p[nt][r] = e;
          rsum[r] += e;
        }
      #pragma unroll
      for (int r = 0; r < 4; r++) {
        float rs = rsum[r];
        rs += __shfl_xor(rs, 1);
        rs += __shfl_xor(rs, 2);
        rs += __shfl_xor(rs, 4);
        rs += __shfl_xor(rs, 8);
        l_i[r] = l_i[r] * alpha[r] + rs;
      }
      #pragma unroll
      for (int dt = 0; dt < 8; dt++)
        #pragma unroll
        for (int r = 0; r < 4; r++) o[dt][r] *= alpha[r];

      #pragma unroll
      for (int nt = 0; nt < 4; nt++)
        #pragma unroll
        for (int r = 0; r < 4; r++)
          Pw[(quad * 4 + r) * VLD + nt * 16 + col] = f2bf(p[nt][r]);
      asm volatile("s_waitcnt lgkmcnt(0)" ::: "memory");
      bf16x8 pf[2];
      #pragma unroll
      for (int kc2 = 0; kc2 < 2; kc2++)
        pf[kc2] = *(const bf16x8*)(&Pw[col * VLD + kc2 * 32 + quad * 8]);

      #pragma unroll
      for (int dt = 0; dt < 8; dt++) {
        #pragma unroll
        for (int kc2 = 0; kc2 < 2; kc2++) {
          bf16x8 vf = *(const bf16x8*)(&Vsm[(dt * 16 + col) * VLD + kc2 * 32 + quad * 8]);
          o[dt] = __builtin_amdgcn_mfma_f32_16x16x32_bf16(pf[kc2], vf, o[dt], 0, 0, 0);
        }
      }
    }
    __syncthreads();
  }

  #pragma unroll
  for (int dt = 0; dt < 8; dt++) {
    int dcol = h * HD + dt * 16 + col;
    #pragma unroll
    for (int r = 0; r < 4; r++) {
      int rg = qrow + quad * 4 + r;
      ao[((size_t)(b * S_LEN) + rg) * DIM_ + dcol] = f2bf(o[dt][r] / l_i[r]);
    }
  }
}

extern "C" void kernel_launch(void* const* d_in, const int* in_sizes, int n_in,
                              void* d_out, int out_size, void* d_ws, size_t ws_size,
                              hipStream_t stream) {
  const float* x  = (const float*)d_in[0];
  const float* fc = (const float*)d_in[1];
  const float* fs = (const float*)d_in[2];
  const float* wq = (const float*)d_in[3];
  const float* wk = (const float*)d_in[4];
  const float* wv = (const float*)d_in[5];
  const float* wo = (const float*)d_in[6];
  float* out = (float*)d_out;

  char* ws = (char*)d_ws;
  const size_t MB = 1024 * 1024;
  unsigned short* xb    = (unsigned short*)(ws + 0 * MB);    // 4096x2048 bf16 (16 MiB)
  unsigned short* wqkvT = (unsigned short*)(ws + 16 * MB);   // 4096x2048      (16 MiB)
  unsigned short* woT   = (unsigned short*)(ws + 32 * MB);   // 2048x2048      (8 MiB)
  unsigned short* qb    = (unsigned short*)(ws + 40 * MB);   // 4096x2048      (16 MiB)
  unsigned short* kb    = (unsigned short*)(ws + 56 * MB);   // 4096x1024      (8 MiB)
  unsigned short* vT    = (unsigned short*)(ws + 64 * MB);   // (b,kvh,d,s)    (8 MiB)
  unsigned short* ao    = (unsigned short*)(ws + 72 * MB);   // 4096x2048      (16 MiB)

  // prep: convert x + transpose-convert all weights (one dispatch)
  k_prep<<<dim3(20480), dim3(256), 0, stream>>>(x, xb, wq, wk, wv, wo, wqkvT, woT);
  // fused QKV projection + RoPE (+q pre-scale) + V transpose
  k_gemm_bt<3><<<dim3(32, 32), dim3(256), 0, stream>>>(xb, wqkvT, (void*)qb, 4096, 2048, fc, fs, kb, vT);
  // attention
  k_attn<<<dim3(32, 16), dim3(512), 0, stream>>>(qb, kb, vT, ao);
  // output projection (f32 out)
  k_gemm_bt<1><<<dim3(16, 32), dim3(256), 0, stream>>>(ao, woT, (void*)out, 2048, 2048, nullptr, nullptr, nullptr, nullptr);
}

// Round 5
// 378.161 us; speedup vs baseline: 1.6891x; 1.0674x over previous
//
#include <hip/hip_runtime.h>
#include <cstdint>
#include <cstddef>

#define S_LEN 2048
#define DIM_   2048
#define NH   16
#define NKV  8
#define HD   128

typedef __attribute__((ext_vector_type(8))) __bf16 bf16x8;
typedef __attribute__((ext_vector_type(4))) float  f32x4;

typedef const __attribute__((address_space(1))) void* gptr_t;
typedef __attribute__((address_space(3))) void*       sptr_t;

static __device__ __forceinline__ float bf2f(unsigned short u) {
  union { unsigned int i; float f; } v; v.i = ((unsigned int)u) << 16; return v.f;
}
static __device__ __forceinline__ unsigned short f2bf(float f) {
  union { float f; unsigned int i; } v; v.f = f;
  unsigned int u = v.i;
  unsigned int r = (u + 0x7FFFu + ((u >> 16) & 1u)) >> 16;
  return (unsigned short)r;
}

// scale(1/sqrt(128)) * log2(e) — folded into q so softmax uses exp2 directly
#define QSCALE 0.12751744f

// ---------------- prep: x->bf16 convert + 4 weight transpose-converts ----------------
__global__ void k_prep(const float* __restrict__ x, unsigned short* __restrict__ xb,
                       const float* __restrict__ wq, const float* __restrict__ wk,
                       const float* __restrict__ wv, const float* __restrict__ wo,
                       unsigned short* __restrict__ wqkvT, unsigned short* __restrict__ woT) {
  int bid = blockIdx.x;
  if (bid < 8192) {
    int i = bid * 256 + threadIdx.x;
    float4 v = ((const float4*)x)[i];
    ushort4 o; o.x = f2bf(v.x); o.y = f2bf(v.y); o.z = f2bf(v.z); o.w = f2bf(v.w);
    ((ushort4*)xb)[i] = o;
    return;
  }
  bid -= 8192;
  const float* src; unsigned short* dst; int N, ntx;
  if (bid < 4096)      { src = wq; dst = wqkvT;                       N = 2048; ntx = 64; }
  else if (bid < 6144) { bid -= 4096; src = wk; dst = wqkvT + (size_t)2048 * 2048; N = 1024; ntx = 32; }
  else if (bid < 8192) { bid -= 6144; src = wv; dst = wqkvT + (size_t)3072 * 2048; N = 1024; ntx = 32; }
  else                 { bid -= 8192; src = wo; dst = woT;            N = 2048; ntx = 64; }
  const int K = 2048;
  __shared__ float tile[32][33];
  int lx = threadIdx.x & 31, ly = threadIdx.x >> 5; // 32 x 8
  int r0 = (bid / ntx) * 32, c0 = (bid % ntx) * 32;
  #pragma unroll
  for (int r = 0; r < 32; r += 8)
    tile[ly + r][lx] = src[(size_t)(r0 + ly + r) * N + c0 + lx];
  __syncthreads();
  #pragma unroll
  for (int r = 0; r < 32; r += 8)
    dst[(size_t)(c0 + ly + r) * K + r0 + lx] = f2bf(tile[lx][ly + r]);
}

// ------------- GEMM: C(MxN) = A(MxK) * BT(NxK)^T, bf16 in, fp32 acc -------------
// BK=64, XOR-swizzled LDS via source permutation (conflict-free, measured 0).
// __launch_bounds__(256,2): VGPR cap 256 so all fragments stay live (m97 parity).
// MODE 1: store f32 natural C[m][n]
// MODE 3: fused QKV epilogue (q+RoPE*QSCALE | k+RoPE | v transposed).
template<int MODE>
__global__ __launch_bounds__(256, 2) void k_gemm_bt(
    const unsigned short* __restrict__ A, const unsigned short* __restrict__ BT,
    void* __restrict__ C, int N, int K,
    const float* __restrict__ fc, const float* __restrict__ fs,
    unsigned short* __restrict__ kb, unsigned short* __restrict__ vb) {
  __shared__ __align__(16) unsigned short Asm[128 * 64];
  __shared__ __align__(16) unsigned short Bsm[128 * 64];
  const int t = threadIdx.x;
  const int lane = t & 63, w = t >> 6;
  const int wm = (w >> 1) * 64, wn = (w & 1) * 64;
  const int col = lane & 15, quad = lane >> 4;
  const int m0 = blockIdx.y * 128, n0 = blockIdx.x * 128;

  f32x4 acc[4][4];
  #pragma unroll
  for (int i = 0; i < 4; i++)
    #pragma unroll
    for (int j = 0; j < 4; j++) acc[i][j] = (f32x4){0.f, 0.f, 0.f, 0.f};

  for (int kk = 0; kk < K; kk += 64) {
    #pragma unroll
    for (int r = 0; r < 4; ++r) {
      int c = t + r * 256;
      int c0 = (t & ~63) + r * 256;   // wave-uniform chunk base
      int row = c >> 3;
      int kcs = (c & 7) ^ (row & 7);  // source permutation = target swizzle
      const unsigned short* gA = A + (size_t)(m0 + row) * K + kk + kcs * 8;
      const unsigned short* gB = BT + (size_t)(n0 + row) * K + kk + kcs * 8;
      __builtin_amdgcn_global_load_lds((gptr_t)gA, (sptr_t)(&Asm[c0 * 8]), 16, 0, 0);
      __builtin_amdgcn_global_load_lds((gptr_t)gB, (sptr_t)(&Bsm[c0 * 8]), 16, 0, 0);
    }
    __syncthreads();
    #pragma unroll
    for (int kc2 = 0; kc2 < 2; kc2++) {
      bf16x8 af[4], bf[4];
      #pragma unroll
      for (int mi = 0; mi < 4; mi++) {
        int rowA = wm + mi * 16 + col;
        af[mi] = *(const bf16x8*)(&Asm[rowA * 64 + (((kc2 * 4 + quad) ^ (col & 7)) * 8)]);
      }
      #pragma unroll
      for (int ni = 0; ni < 4; ni++) {
        int rowB = wn + ni * 16 + col;
        bf[ni] = *(const bf16x8*)(&Bsm[rowB * 64 + (((kc2 * 4 + quad) ^ (col & 7)) * 8)]);
      }
      #pragma unroll
      for (int mi = 0; mi < 4; mi++)
        #pragma unroll
        for (int ni = 0; ni < 4; ni++)
          acc[mi][ni] = __builtin_amdgcn_mfma_f32_16x16x32_bf16(af[mi], bf[ni], acc[mi][ni], 0, 0, 0);
    }
    __syncthreads();
  }

  #pragma unroll
  for (int mi = 0; mi < 4; mi++) {
    int row_base = m0 + wm + mi * 16 + quad * 4;
    #pragma unroll
    for (int ni = 0; ni < 4; ni++) {
      int col_g = n0 + wn + ni * 16 + col;
      if (MODE == 1) {
        float* O = (float*)C;
        #pragma unroll
        for (int r = 0; r < 4; r++) O[(size_t)(row_base + r) * N + col_g] = acc[mi][ni][r];
      } else {  // MODE 3
        int region = col_g >> 10;  // 0,1: q ; 2: k ; 3: v
        if (region < 3) {
          int ri = (col_g & 127) >> 1;
          float sgn = (col_g & 1) ? 1.f : -1.f;
          unsigned short* qO = (unsigned short*)C;
          #pragma unroll
          for (int r = 0; r < 4; r++) {
            int row = row_base + r;
            int s = row & (S_LEN - 1);
            float cv = fc[s * 64 + ri], sv = fs[s * 64 + ri];
            float val = acc[mi][ni][r];
            float other = __shfl_xor(val, 1);
            float res = val * cv + sgn * other * sv;
            if (region < 2) qO[(size_t)row * 2048 + col_g] = f2bf(res * QSCALE);
            else            kb[(size_t)row * 1024 + (col_g - 2048)] = f2bf(res);
          }
        } else {
          int n_local = col_g - 3072;
          int b = row_base >> 11, s = row_base & (S_LEN - 1);
          int kvh = n_local >> 7, d = n_local & (HD - 1);
          ushort4 o4;
          o4.x = f2bf(acc[mi][ni][0]); o4.y = f2bf(acc[mi][ni][1]);
          o4.z = f2bf(acc[mi][ni][2]); o4.w = f2bf(acc[mi][ni][3]);
          *(ushort4*)(&vb[((size_t)((b * NKV + kvh) * HD + d)) * S_LEN + s]) = o4;
        }
      }
    }
  }
}

// ---------------- Flash attention, causal, GQA (kvh = h>>1) ----------------
// 512-thread blocks, 8 waves: waves 0-3 own q-tile y, waves 4-7 own 31-y.
// Processes 128 keys (a pair of 64-key tiles) per online-softmax update:
// o-rescale / max-sum shfl chains / l-update amortized over 2x keys, and
// 3 barriers per 128 keys (vs 4). P aliases into Ksm (8 waves x 16 rows = 128).
#define KLD 136   // 128 + 8 (row-to-row bank offset 4 -> conflict-free frags)
__global__ __launch_bounds__(512, 4) void k_attn(
    const unsigned short* __restrict__ q, const unsigned short* __restrict__ k,
    const unsigned short* __restrict__ vT, unsigned short* __restrict__ ao) {
  __shared__ __align__(16) unsigned short Ksm[128 * KLD];  // keys x d; P aliases after QK^T
  __shared__ __align__(16) unsigned short Vsm[128 * KLD];  // d x keys
  const int t = threadIdx.x;
  const int lane = t & 63, w = t >> 6;
  const int col = lane & 15, quad = lane >> 4;
  const int bh = blockIdx.x;
  const int b = bh >> 4, h = bh & 15, kvh = h >> 1;
  const int y = blockIdx.y;                   // 0..15
  const int my_qt = (w < 4) ? y : (31 - y);
  const int qrow = my_qt * 64 + (w & 3) * 16;
  unsigned short* Pw = &Ksm[w * 16 * KLD];    // wave-private P rows (16 x 128 keys)

  bf16x8 qf[4];
  const size_t qbase = ((size_t)(b * S_LEN) + qrow + col) * DIM_ + h * HD;
  #pragma unroll
  for (int kc = 0; kc < 4; kc++) qf[kc] = *(const bf16x8*)(q + qbase + kc * 32 + quad * 8);

  f32x4 o[8];
  #pragma unroll
  for (int i = 0; i < 8; i++) o[i] = (f32x4){0.f, 0.f, 0.f, 0.f};
  float m_i[4] = {-1e30f, -1e30f, -1e30f, -1e30f};
  float l_i[4] = {0.f, 0.f, 0.f, 0.f};

  const int last_pt = my_qt >> 1;             // this wave's final (diagonal) pair
  const int npairs = ((31 - y) >> 1) + 1;     // staging covers the longest wave
  for (int pt = 0; pt < npairs; ++pt) {
    // stage K pair-tile (128 keys x 128 d) and V^T pair-tile (128 d x 128 keys)
    #pragma unroll
    for (int r = 0; r < 4; ++r) {
      int c = t + r * 512;
      int i = c >> 4, dc = c & 15;
      *(uint4*)(&Ksm[i * KLD + dc * 8]) =
          *(const uint4*)(k + ((size_t)(b * S_LEN + pt * 128 + i)) * (NKV * HD) + kvh * HD + dc * 8);
      *(uint4*)(&Vsm[i * KLD + dc * 8]) =
          *(const uint4*)(vT + ((size_t)((b * NKV + kvh) * HD + i)) * S_LEN + pt * 128 + dc * 8);
    }
    __syncthreads();

    const bool active = (pt <= last_pt);      // wave-uniform
    float p[8][4];
    float mnew[4], alpha[4];
    if (active) {
      #pragma unroll
      for (int nt = 0; nt < 8; nt++) {
        f32x4 s_acc = (f32x4){0.f, 0.f, 0.f, 0.f};
        #pragma unroll
        for (int kc = 0; kc < 4; kc++) {
          bf16x8 kf = *(const bf16x8*)(&Ksm[(nt * 16 + col) * KLD + kc * 32 + quad * 8]);
          s_acc = __builtin_amdgcn_mfma_f32_16x16x32_bf16(qf[kc], kf, s_acc, 0, 0, 0);
        }
        #pragma unroll
        for (int r = 0; r < 4; r++) p[nt][r] = s_acc[r];
      }
      if (pt == last_pt) {                    // pair containing the diagonal
        #pragma unroll
        for (int nt = 0; nt < 8; nt++) {
          int key = pt * 128 + nt * 16 + col;
          #pragma unroll
          for (int r = 0; r < 4; r++) {
            int rg = qrow + quad * 4 + r;
            if (key > rg) p[nt][r] = -1e30f;
          }
        }
      }
      #pragma unroll
      for (int r = 0; r < 4; r++) {
        float mx = p[0][r];
        #pragma unroll
        for (int nt = 1; nt < 8; nt++) mx = fmaxf(mx, p[nt][r]);
        mx = fmaxf(mx, __shfl_xor(mx, 1));
        mx = fmaxf(mx, __shfl_xor(mx, 2));
        mx = fmaxf(mx, __shfl_xor(mx, 4));
        mx = fmaxf(mx, __shfl_xor(mx, 8));
        mnew[r] = fmaxf(m_i[r], mx);
        alpha[r] = exp2f(m_i[r] - mnew[r]);
        m_i[r] = mnew[r];
      }
      float rsum[4] = {0.f, 0.f, 0.f, 0.f};
      #pragma unroll
      for (int nt = 0; nt < 8; nt++)
        #pragma unroll
        for (int r = 0; r < 4; r++) {
          float e = exp2f(p[nt][r] - mnew[r]);
          p[nt][r] = e;
          rsum[r] += e;
        }
      #pragma unroll
      for (int r = 0; r < 4; r++) {
        float rs = rsum[r];
        rs += __shfl_xor(rs, 1);
        rs += __shfl_xor(rs, 2);
        rs += __shfl_xor(rs, 4);
        rs += __shfl_xor(rs, 8);
        l_i[r] = l_i[r] * alpha[r] + rs;
      }
      #pragma unroll
      for (int dt = 0; dt < 8; dt++)
        #pragma unroll
        for (int r = 0; r < 4; r++) o[dt][r] *= alpha[r];
    }

    __syncthreads();   // all QK^T reads of Ksm done -> safe to overwrite with P

    if (active) {
      #pragma unroll
      for (int nt = 0; nt < 8; nt++)
        #pragma unroll
        for (int r = 0; r < 4; r++)
          Pw[(quad * 4 + r) * KLD + nt * 16 + col] = f2bf(p[nt][r]);
      asm volatile("s_waitcnt lgkmcnt(0)" ::: "memory");  // wave-internal RAW
      bf16x8 pf[4];
      #pragma unroll
      for (int kc2 = 0; kc2 < 4; kc2++)
        pf[kc2] = *(const bf16x8*)(&Pw[col * KLD + kc2 * 32 + quad * 8]);

      #pragma unroll
      for (int dt = 0; dt < 8; dt++) {
        #pragma unroll
        for (int kc2 = 0; kc2 < 4; kc2++) {
          bf16x8 vf = *(const bf16x8*)(&Vsm[(dt * 16 + col) * KLD + kc2 * 32 + quad * 8]);
          o[dt] = __builtin_amdgcn_mfma_f32_16x16x32_bf16(pf[kc2], vf, o[dt], 0, 0, 0);
        }
      }
    }
    __syncthreads();   // before next staging overwrites Ksm/Vsm
  }

  #pragma unroll
  for (int dt = 0; dt < 8; dt++) {
    int dcol = h * HD + dt * 16 + col;
    #pragma unroll
    for (int r = 0; r < 4; r++) {
      int rg = qrow + quad * 4 + r;
      ao[((size_t)(b * S_LEN) + rg) * DIM_ + dcol] = f2bf(o[dt][r] / l_i[r]);
    }
  }
}

extern "C" void kernel_launch(void* const* d_in, const int* in_sizes, int n_in,
                              void* d_out, int out_size, void* d_ws, size_t ws_size,
                              hipStream_t stream) {
  const float* x  = (const float*)d_in[0];
  const float* fc = (const float*)d_in[1];
  const float* fs = (const float*)d_in[2];
  const float* wq = (const float*)d_in[3];
  const float* wk = (const float*)d_in[4];
  const float* wv = (const float*)d_in[5];
  const float* wo = (const float*)d_in[6];
  float* out = (float*)d_out;

  char* ws = (char*)d_ws;
  const size_t MB = 1024 * 1024;
  unsigned short* xb    = (unsigned short*)(ws + 0 * MB);    // 4096x2048 bf16 (16 MiB)
  unsigned short* wqkvT = (unsigned short*)(ws + 16 * MB);   // 4096x2048      (16 MiB)
  unsigned short* woT   = (unsigned short*)(ws + 32 * MB);   // 2048x2048      (8 MiB)
  unsigned short* qb    = (unsigned short*)(ws + 40 * MB);   // 4096x2048      (16 MiB)
  unsigned short* kb    = (unsigned short*)(ws + 56 * MB);   // 4096x1024      (8 MiB)
  unsigned short* vT    = (unsigned short*)(ws + 64 * MB);   // (b,kvh,d,s)    (8 MiB)
  unsigned short* ao    = (unsigned short*)(ws + 72 * MB);   // 4096x2048      (16 MiB)

  // prep: convert x + transpose-convert all weights (one dispatch)
  k_prep<<<dim3(20480), dim3(256), 0, stream>>>(x, xb, wq, wk, wv, wo, wqkvT, woT);
  // fused QKV projection + RoPE (+q pre-scale) + V transpose
  k_gemm_bt<3><<<dim3(32, 32), dim3(256), 0, stream>>>(xb, wqkvT, (void*)qb, 4096, 2048, fc, fs, kb, vT);
  // attention
  k_attn<<<dim3(32, 16), dim3(512), 0, stream>>>(qb, kb, vT, ao);
  // output projection (f32 out)
  k_gemm_bt<1><<<dim3(16, 32), dim3(256), 0, stream>>>(ao, woT, (void*)out, 2048, 2048, nullptr, nullptr, nullptr, nullptr);
}

// Round 6
// 357.636 us; speedup vs baseline: 1.7860x; 1.0574x over previous
//
#include <hip/hip_runtime.h>
#include <cstdint>
#include <cstddef>

#define S_LEN 2048
#define DIM_   2048
#define NH   16
#define NKV  8
#define HD   128

typedef __attribute__((ext_vector_type(8))) __bf16 bf16x8;
typedef __attribute__((ext_vector_type(4))) float  f32x4;

typedef const __attribute__((address_space(1))) void* gptr_t;
typedef __attribute__((address_space(3))) void*       sptr_t;

static __device__ __forceinline__ float bf2f(unsigned short u) {
  union { unsigned int i; float f; } v; v.i = ((unsigned int)u) << 16; return v.f;
}
static __device__ __forceinline__ unsigned short f2bf(float f) {
  union { float f; unsigned int i; } v; v.f = f;
  unsigned int u = v.i;
  unsigned int r = (u + 0x7FFFu + ((u >> 16) & 1u)) >> 16;
  return (unsigned short)r;
}

// scale(1/sqrt(128)) * log2(e) — folded into q so softmax uses exp2 directly
#define QSCALE 0.12751744f

// ---------------- prep: x->bf16 convert + 4 weight transpose-converts ----------------
__global__ void k_prep(const float* __restrict__ x, unsigned short* __restrict__ xb,
                       const float* __restrict__ wq, const float* __restrict__ wk,
                       const float* __restrict__ wv, const float* __restrict__ wo,
                       unsigned short* __restrict__ wqkvT, unsigned short* __restrict__ woT) {
  int bid = blockIdx.x;
  if (bid < 8192) {
    int i = bid * 256 + threadIdx.x;
    float4 v = ((const float4*)x)[i];
    ushort4 o; o.x = f2bf(v.x); o.y = f2bf(v.y); o.z = f2bf(v.z); o.w = f2bf(v.w);
    ((ushort4*)xb)[i] = o;
    return;
  }
  bid -= 8192;
  const float* src; unsigned short* dst; int N, ntx;
  if (bid < 4096)      { src = wq; dst = wqkvT;                       N = 2048; ntx = 64; }
  else if (bid < 6144) { bid -= 4096; src = wk; dst = wqkvT + (size_t)2048 * 2048; N = 1024; ntx = 32; }
  else if (bid < 8192) { bid -= 6144; src = wv; dst = wqkvT + (size_t)3072 * 2048; N = 1024; ntx = 32; }
  else                 { bid -= 8192; src = wo; dst = woT;            N = 2048; ntx = 64; }
  const int K = 2048;
  __shared__ float tile[32][33];
  int lx = threadIdx.x & 31, ly = threadIdx.x >> 5; // 32 x 8
  int r0 = (bid / ntx) * 32, c0 = (bid % ntx) * 32;
  #pragma unroll
  for (int r = 0; r < 32; r += 8)
    tile[ly + r][lx] = src[(size_t)(r0 + ly + r) * N + c0 + lx];
  __syncthreads();
  #pragma unroll
  for (int r = 0; r < 32; r += 8)
    dst[(size_t)(c0 + ly + r) * K + r0 + lx] = f2bf(tile[lx][ly + r]);
}

// ------------- GEMM: C(MxN) = A(MxK) * BT(NxK)^T, bf16 in, fp32 acc -------------
// BK=64, XOR-swizzled LDS via source permutation (conflict-free, measured 0).
// __launch_bounds__(256,2): VGPR cap 256 so all fragments stay live.
// MODE 1: store f32 natural C[m][n]
// MODE 3: fused QKV epilogue (q+RoPE*QSCALE | k+RoPE | v transposed).
template<int MODE>
__global__ __launch_bounds__(256, 2) void k_gemm_bt(
    const unsigned short* __restrict__ A, const unsigned short* __restrict__ BT,
    void* __restrict__ C, int N, int K,
    const float* __restrict__ fc, const float* __restrict__ fs,
    unsigned short* __restrict__ kb, unsigned short* __restrict__ vb) {
  __shared__ __align__(16) unsigned short Asm[128 * 64];
  __shared__ __align__(16) unsigned short Bsm[128 * 64];
  const int t = threadIdx.x;
  const int lane = t & 63, w = t >> 6;
  const int wm = (w >> 1) * 64, wn = (w & 1) * 64;
  const int col = lane & 15, quad = lane >> 4;
  const int m0 = blockIdx.y * 128, n0 = blockIdx.x * 128;

  f32x4 acc[4][4];
  #pragma unroll
  for (int i = 0; i < 4; i++)
    #pragma unroll
    for (int j = 0; j < 4; j++) acc[i][j] = (f32x4){0.f, 0.f, 0.f, 0.f};

  for (int kk = 0; kk < K; kk += 64) {
    #pragma unroll
    for (int r = 0; r < 4; ++r) {
      int c = t + r * 256;
      int c0 = (t & ~63) + r * 256;   // wave-uniform chunk base
      int row = c >> 3;
      int kcs = (c & 7) ^ (row & 7);  // source permutation = target swizzle
      const unsigned short* gA = A + (size_t)(m0 + row) * K + kk + kcs * 8;
      const unsigned short* gB = BT + (size_t)(n0 + row) * K + kk + kcs * 8;
      __builtin_amdgcn_global_load_lds((gptr_t)gA, (sptr_t)(&Asm[c0 * 8]), 16, 0, 0);
      __builtin_amdgcn_global_load_lds((gptr_t)gB, (sptr_t)(&Bsm[c0 * 8]), 16, 0, 0);
    }
    __syncthreads();
    #pragma unroll
    for (int kc2 = 0; kc2 < 2; kc2++) {
      bf16x8 af[4], bf[4];
      #pragma unroll
      for (int mi = 0; mi < 4; mi++) {
        int rowA = wm + mi * 16 + col;
        af[mi] = *(const bf16x8*)(&Asm[rowA * 64 + (((kc2 * 4 + quad) ^ (col & 7)) * 8)]);
      }
      #pragma unroll
      for (int ni = 0; ni < 4; ni++) {
        int rowB = wn + ni * 16 + col;
        bf[ni] = *(const bf16x8*)(&Bsm[rowB * 64 + (((kc2 * 4 + quad) ^ (col & 7)) * 8)]);
      }
      #pragma unroll
      for (int mi = 0; mi < 4; mi++)
        #pragma unroll
        for (int ni = 0; ni < 4; ni++)
          acc[mi][ni] = __builtin_amdgcn_mfma_f32_16x16x32_bf16(af[mi], bf[ni], acc[mi][ni], 0, 0, 0);
    }
    __syncthreads();
  }

  #pragma unroll
  for (int mi = 0; mi < 4; mi++) {
    int row_base = m0 + wm + mi * 16 + quad * 4;
    #pragma unroll
    for (int ni = 0; ni < 4; ni++) {
      int col_g = n0 + wn + ni * 16 + col;
      if (MODE == 1) {
        float* O = (float*)C;
        #pragma unroll
        for (int r = 0; r < 4; r++) O[(size_t)(row_base + r) * N + col_g] = acc[mi][ni][r];
      } else {  // MODE 3
        int region = col_g >> 10;  // 0,1: q ; 2: k ; 3: v
        if (region < 3) {
          int ri = (col_g & 127) >> 1;
          float sgn = (col_g & 1) ? 1.f : -1.f;
          unsigned short* qO = (unsigned short*)C;
          #pragma unroll
          for (int r = 0; r < 4; r++) {
            int row = row_base + r;
            int s = row & (S_LEN - 1);
            float cv = fc[s * 64 + ri], sv = fs[s * 64 + ri];
            float val = acc[mi][ni][r];
            float other = __shfl_xor(val, 1);
            float res = val * cv + sgn * other * sv;
            if (region < 2) qO[(size_t)row * 2048 + col_g] = f2bf(res * QSCALE);
            else            kb[(size_t)row * 1024 + (col_g - 2048)] = f2bf(res);
          }
        } else {
          int n_local = col_g - 3072;
          int b = row_base >> 11, s = row_base & (S_LEN - 1);
          int kvh = n_local >> 7, d = n_local & (HD - 1);
          ushort4 o4;
          o4.x = f2bf(acc[mi][ni][0]); o4.y = f2bf(acc[mi][ni][1]);
          o4.z = f2bf(acc[mi][ni][2]); o4.w = f2bf(acc[mi][ni][3]);
          *(ushort4*)(&vb[((size_t)((b * NKV + kvh) * HD + d)) * S_LEN + s]) = o4;
        }
      }
    }
  }
}

// ---------------- Flash attention, causal, GQA-shared K/V ----------------
// 1024-thread blocks (16 waves): waves 0-3 = head 2g @ q-tile y, 4-7 = head 2g+1
// @ y, 8-11 = head 2g @ 31-y, 12-15 = head 2g+1 @ 31-y. One K/V staging serves
// 4 wave-groups (2 heads x 2 q-tiles) -> staging bytes halved vs per-head blocks,
// and block duration is uniform (y & 31-y pairing). Grid (16 kv-groups, 16) =
// 256 blocks = 1 per CU. 64-key tiles, p[4][4] per wave (register-safe, no spill).
#define KLD 136   // 128 + 8 (row-to-row bank offset 4 -> conflict-free frags)
#define VLD 72    // 64 + 8
__global__ __launch_bounds__(1024) void k_attn(
    const unsigned short* __restrict__ q, const unsigned short* __restrict__ k,
    const unsigned short* __restrict__ vT, unsigned short* __restrict__ ao) {
  __shared__ __align__(16) unsigned short Ksm[64 * KLD];       // 17408 B
  __shared__ __align__(16) unsigned short Vsm[128 * VLD];      // 18432 B
  __shared__ __align__(16) unsigned short Psm[16 * 16 * VLD];  // 36864 B
  const int t = threadIdx.x;
  const int lane = t & 63, w = t >> 6;        // 16 waves
  const int col = lane & 15, quad = lane >> 4;
  const int g = blockIdx.x;                   // b*NKV + kvh
  const int b = g >> 3, kvh = g & 7;
  const int h = kvh * 2 + ((w >> 2) & 1);     // this wave's head
  const int y = blockIdx.y;                   // 0..15
  const int my_qt = (w < 8) ? y : (31 - y);
  const int qrow = my_qt * 64 + (w & 3) * 16; // this wave's 16 query rows
  unsigned short* Pw = &Psm[w * 16 * VLD];

  bf16x8 qf[4];
  const size_t qbase = ((size_t)(b * S_LEN) + qrow + col) * DIM_ + h * HD;
  #pragma unroll
  for (int kc = 0; kc < 4; kc++) qf[kc] = *(const bf16x8*)(q + qbase + kc * 32 + quad * 8);

  f32x4 o[8];
  #pragma unroll
  for (int i = 0; i < 8; i++) o[i] = (f32x4){0.f, 0.f, 0.f, 0.f};
  float m_i[4] = {-1e30f, -1e30f, -1e30f, -1e30f};
  float l_i[4] = {0.f, 0.f, 0.f, 0.f};

  const int nkt = 32 - y;   // covers the longest group (my_qt = 31-y)
  for (int kt = 0; kt < nkt; ++kt) {
    // stage K tile (64 keys x 128 d) and V^T tile (128 d x 64 keys): 1 uint4
    // per thread per matrix (1024 threads)
    { int i = t >> 4, dc = t & 15;
      *(uint4*)(&Ksm[i * KLD + dc * 8]) =
          *(const uint4*)(k + ((size_t)(b * S_LEN + kt * 64 + i)) * (NKV * HD) + kvh * HD + dc * 8);
      int d = t >> 3, kc2 = t & 7;
      *(uint4*)(&Vsm[d * VLD + kc2 * 8]) =
          *(const uint4*)(vT + ((size_t)((b * NKV + kvh) * HD + d)) * S_LEN + kt * 64 + kc2 * 8);
    }
    __syncthreads();

    if (kt <= my_qt) {   // wave-uniform causal range
      float p[4][4];
      #pragma unroll
      for (int nt = 0; nt < 4; nt++) {
        f32x4 s_acc = (f32x4){0.f, 0.f, 0.f, 0.f};
        #pragma unroll
        for (int kc = 0; kc < 4; kc++) {
          bf16x8 kf = *(const bf16x8*)(&Ksm[(nt * 16 + col) * KLD + kc * 32 + quad * 8]);
          s_acc = __builtin_amdgcn_mfma_f32_16x16x32_bf16(qf[kc], kf, s_acc, 0, 0, 0);
        }
        #pragma unroll
        for (int r = 0; r < 4; r++) p[nt][r] = s_acc[r];
      }
      if (kt == my_qt) {  // diagonal tile: causal mask
        #pragma unroll
        for (int nt = 0; nt < 4; nt++) {
          int key = kt * 64 + nt * 16 + col;
          #pragma unroll
          for (int r = 0; r < 4; r++) {
            int rg = qrow + quad * 4 + r;
            if (key > rg) p[nt][r] = -1e30f;
          }
        }
      }
      float mnew[4], alpha[4];
      #pragma unroll
      for (int r = 0; r < 4; r++) {
        float mx = fmaxf(fmaxf(p[0][r], p[1][r]), fmaxf(p[2][r], p[3][r]));
        mx = fmaxf(mx, __shfl_xor(mx, 1));
        mx = fmaxf(mx, __shfl_xor(mx, 2));
        mx = fmaxf(mx, __shfl_xor(mx, 4));
        mx = fmaxf(mx, __shfl_xor(mx, 8));
        mnew[r] = fmaxf(m_i[r], mx);
        alpha[r] = exp2f(m_i[r] - mnew[r]);
        m_i[r] = mnew[r];
      }
      float rsum[4] = {0.f, 0.f, 0.f, 0.f};
      #pragma unroll
      for (int nt = 0; nt < 4; nt++)
        #pragma unroll
        for (int r = 0; r < 4; r++) {
          float e = exp2f(p[nt][r] - mnew[r]);
          p[nt][r] = e;
          rsum[r] += e;
        }
      #pragma unroll
      for (int r = 0; r < 4; r++) {
        float rs = rsum[r];
        rs += __shfl_xor(rs, 1);
        rs += __shfl_xor(rs, 2);
        rs += __shfl_xor(rs, 4);
        rs += __shfl_xor(rs, 8);
        l_i[r] = l_i[r] * alpha[r] + rs;
      }
      #pragma unroll
      for (int dt = 0; dt < 8; dt++)
        #pragma unroll
        for (int r = 0; r < 4; r++) o[dt][r] *= alpha[r];

      // P: C-layout -> A-layout via wave-private LDS round trip
      #pragma unroll
      for (int nt = 0; nt < 4; nt++)
        #pragma unroll
        for (int r = 0; r < 4; r++)
          Pw[(quad * 4 + r) * VLD + nt * 16 + col] = f2bf(p[nt][r]);
      asm volatile("s_waitcnt lgkmcnt(0)" ::: "memory");  // wave-internal RAW
      bf16x8 pf[2];
      #pragma unroll
      for (int kc2 = 0; kc2 < 2; kc2++)
        pf[kc2] = *(const bf16x8*)(&Pw[col * VLD + kc2 * 32 + quad * 8]);

      // O += P V
      #pragma unroll
      for (int dt = 0; dt < 8; dt++) {
        #pragma unroll
        for (int kc2 = 0; kc2 < 2; kc2++) {
          bf16x8 vf = *(const bf16x8*)(&Vsm[(dt * 16 + col) * VLD + kc2 * 32 + quad * 8]);
          o[dt] = __builtin_amdgcn_mfma_f32_16x16x32_bf16(pf[kc2], vf, o[dt], 0, 0, 0);
        }
      }
    }
    __syncthreads();
  }

  #pragma unroll
  for (int dt = 0; dt < 8; dt++) {
    int dcol = h * HD + dt * 16 + col;
    #pragma unroll
    for (int r = 0; r < 4; r++) {
      int rg = qrow + quad * 4 + r;
      ao[((size_t)(b * S_LEN) + rg) * DIM_ + dcol] = f2bf(o[dt][r] / l_i[r]);
    }
  }
}

extern "C" void kernel_launch(void* const* d_in, const int* in_sizes, int n_in,
                              void* d_out, int out_size, void* d_ws, size_t ws_size,
                              hipStream_t stream) {
  const float* x  = (const float*)d_in[0];
  const float* fc = (const float*)d_in[1];
  const float* fs = (const float*)d_in[2];
  const float* wq = (const float*)d_in[3];
  const float* wk = (const float*)d_in[4];
  const float* wv = (const float*)d_in[5];
  const float* wo = (const float*)d_in[6];
  float* out = (float*)d_out;

  char* ws = (char*)d_ws;
  const size_t MB = 1024 * 1024;
  unsigned short* xb    = (unsigned short*)(ws + 0 * MB);    // 4096x2048 bf16 (16 MiB)
  unsigned short* wqkvT = (unsigned short*)(ws + 16 * MB);   // 4096x2048      (16 MiB)
  unsigned short* woT   = (unsigned short*)(ws + 32 * MB);   // 2048x2048      (8 MiB)
  unsigned short* qb    = (unsigned short*)(ws + 40 * MB);   // 4096x2048      (16 MiB)
  unsigned short* kb    = (unsigned short*)(ws + 56 * MB);   // 4096x1024      (8 MiB)
  unsigned short* vT    = (unsigned short*)(ws + 64 * MB);   // (b,kvh,d,s)    (8 MiB)
  unsigned short* ao    = (unsigned short*)(ws + 72 * MB);   // 4096x2048      (16 MiB)

  // prep: convert x + transpose-convert all weights (one dispatch)
  k_prep<<<dim3(20480), dim3(256), 0, stream>>>(x, xb, wq, wk, wv, wo, wqkvT, woT);
  // fused QKV projection + RoPE (+q pre-scale) + V transpose
  k_gemm_bt<3><<<dim3(32, 32), dim3(256), 0, stream>>>(xb, wqkvT, (void*)qb, 4096, 2048, fc, fs, kb, vT);
  // attention (GQA-shared K/V staging, 1 block/CU, balanced)
  k_attn<<<dim3(16, 16), dim3(1024), 0, stream>>>(qb, kb, vT, ao);
  // output projection (f32 out)
  k_gemm_bt<1><<<dim3(16, 32), dim3(256), 0, stream>>>(ao, woT, (void*)out, 2048, 2048, nullptr, nullptr, nullptr, nullptr);
}